// Round 2
// baseline (443.421 us; speedup 1.0000x reference)
//
#include <hip/hip_runtime.h>
#include <math.h>

// Problem constants: B=128,N=8 -> M=1024 rows; D=768; T=512; V=49408
#define VDIM    49408
#define NCH     193          // 49408 / 256 v-chunks
#define NSPLIT  16           // V splits; s = blockIdx&15 -> all 16 WGs of split on XCD s%8
#define NQT     16           // 1024 / 64 query tiles

typedef __bf16 bf16;
typedef __bf16 bf16x8 __attribute__((ext_vector_type(8)));
typedef float  f32x4  __attribute__((ext_vector_type(4)));

// ---------------- Kernel A: kw = audio@W + b, row-normalize -> kwn (bf16) ----
__global__ __launch_bounds__(256) void k_proj(const float* __restrict__ audio,
        const float* __restrict__ W, const float* __restrict__ bias,
        bf16* __restrict__ kwn) {
    __shared__ float a_lds[4 * 768];
    __shared__ float kw_lds[4 * 512];
    __shared__ float rn_lds[4];
    const int tid = threadIdx.x;
    const int q0 = blockIdx.x * 4;

    const float4* asrc = (const float4*)(audio + q0 * 768);
    float4* adst = (float4*)a_lds;
    #pragma unroll
    for (int i = 0; i < 3; ++i) adst[i * 256 + tid] = asrc[i * 256 + tid];
    __syncthreads();

    float acc0[4] = {0.f, 0.f, 0.f, 0.f}, acc1[4] = {0.f, 0.f, 0.f, 0.f};
    #pragma unroll 4
    for (int d = 0; d < 768; ++d) {
        const float w0 = W[d * 512 + tid];
        const float w1 = W[d * 512 + 256 + tid];
        #pragma unroll
        for (int q = 0; q < 4; ++q) {
            const float a = a_lds[q * 768 + d];   // broadcast, conflict-free
            acc0[q] = fmaf(a, w0, acc0[q]);
            acc1[q] = fmaf(a, w1, acc1[q]);
        }
    }
    const float b0 = bias[tid], b1 = bias[256 + tid];
    #pragma unroll
    for (int q = 0; q < 4; ++q) {
        kw_lds[q * 512 + tid]       = acc0[q] + b0;
        kw_lds[q * 512 + 256 + tid] = acc1[q] + b1;
    }
    __syncthreads();

    const int w = tid >> 6, lane = tid & 63;
    {   // wave w handles row w
        float ss = 0.f;
        #pragma unroll
        for (int i = 0; i < 8; ++i) { const float x = kw_lds[w * 512 + lane + i * 64]; ss = fmaf(x, x, ss); }
        #pragma unroll
        for (int o = 1; o < 64; o <<= 1) ss += __shfl_xor(ss, o);
        if (lane == 0) rn_lds[w] = 1.0f / fmaxf(sqrtf(ss), 1e-8f);
    }
    __syncthreads();
    #pragma unroll
    for (int i = 0; i < 8; ++i) {
        const int idx = i * 256 + tid;
        const int q = idx >> 9;
        kwn[(q0 + q) * 512 + (idx & 511)] = (bf16)(kw_lds[idx] * rn_lds[q]);
    }
}

// ---------------- Kernel B: one-pass emb prep --------------------------------
__global__ __launch_bounds__(256) void k_prep(const float* __restrict__ emb,
        bf16* __restrict__ embS, bf16* __restrict__ embT, float* __restrict__ rs) {
    __shared__ unsigned short tile[64 * 512];
    __shared__ float pnorm[64 * 2];
    const int tid = threadIdx.x;
    const int b = blockIdx.x;
    const int v0 = b * 64;
    const int lane = tid & 63;
    const int p = (tid >> 6) & 1;          // wave parity within row

    // 1: coalesced load + fp32 norm partials + bf16 convert + swizzled LDS store
    const float4* src = (const float4*)(emb + (size_t)v0 * 512);
    #pragma unroll
    for (int i = 0; i < 32; ++i) {
        const int L = i * 256 + tid;           // float4 index in 64x128
        const int r = L >> 7, c4 = L & 127;    // whole wave shares one row r
        const float4 x = src[L];
        float ss = x.x * x.x + x.y * x.y + x.z * x.z + x.w * x.w;
        #pragma unroll
        for (int o = 1; o < 64; o <<= 1) ss += __shfl_xor(ss, o);
        if (lane == 0) pnorm[r * 2 + p] = ss;
        const int g = c4 >> 1, half = c4 & 1;
        ushort4 u;
        u.x = __builtin_bit_cast(unsigned short, (bf16)x.x);
        u.y = __builtin_bit_cast(unsigned short, (bf16)x.y);
        u.z = __builtin_bit_cast(unsigned short, (bf16)x.z);
        u.w = __builtin_bit_cast(unsigned short, (bf16)x.w);
        *(ushort4*)&tile[r * 512 + (((g ^ (r & 7)) << 3) + half * 4)] = u;
    }
    __syncthreads();
    if (tid < 64) {
        const float ss = pnorm[tid * 2] + pnorm[tid * 2 + 1];
        // folds 1/TEMP (=10) AND log2(e): producer uses exp2f
        rs[v0 + tid] = 14.426950408889634f / fmaxf(sqrtf(ss), 1e-8f);
    }

    // 2: embS frag-major (uint4 LDS reads, fully coalesced global writes)
    #pragma unroll
    for (int i = 0; i < 16; ++i) {
        const int F = i * 256 + tid;           // out granule 0..4095
        const int frag = F >> 6, l = F & 63;
        const int vt = frag >> 4, kf = frag & 15;
        const int lm = l & 15, lg = l >> 4;
        const int r = vt * 16 + lm, g = kf * 4 + lg;
        const uint4 d = *(const uint4*)&tile[r * 512 + ((g ^ (r & 7)) << 3)];
        *(uint4*)((unsigned short*)embS + ((size_t)(b * 4 + vt) * 16 + kf) * 512 + l * 8) = d;
    }
    // 3: embT frag-major (transpose gather from LDS, coalesced writes)
    #pragma unroll
    for (int i = 0; i < 16; ++i) {
        const int F = i * 256 + tid;
        const int frag = F >> 6, l = F & 63;
        const int kvl = frag >> 5, tt = frag & 31;
        const int lm = l & 15, lg = l >> 4;
        const int t = tt * 16 + lm;
        unsigned short e[8];
        #pragma unroll
        for (int j = 0; j < 8; ++j) {
            const int r = kvl * 32 + lg * 8 + j;
            e[j] = tile[r * 512 + ((((t >> 3) ^ (r & 7)) << 3) + (t & 7))];
        }
        uint4 o;
        o.x = (unsigned)e[0] | ((unsigned)e[1] << 16);
        o.y = (unsigned)e[2] | ((unsigned)e[3] << 16);
        o.z = (unsigned)e[4] | ((unsigned)e[5] << 16);
        o.w = (unsigned)e[6] | ((unsigned)e[7] << 16);
        const int kvg = b * 2 + kvl;           // global v/32 index
        *(uint4*)((unsigned short*)embT + ((size_t)kvg * 32 + tt) * 512 + l * 8) = o;
    }
}

// ---------------- Kernel C: M64 8P+8C producer/consumer fused attention ------
// 1024 threads = 16 waves (4/SIMD, 2 producers + 2 consumers each). Producer p
// (waves 0-7): v-slice p*32 (= exactly consumer kf-granule p), S^T = En@Qn^T
// swapped operands -> lane holds 4 consecutive v -> exp2 + conflict-free packed
// ds_write_b64 directly in consumer frag layout. Distance-2 (3-buffer) E
// prefetch covers L3 latency. Consumers (waves 8-15): O += P@E, 64-wide
// t-slice each, distance-2 ET prefetch. Per-producer(=per-kf) flags both
// directions: consumer waits producer p right before kf p and releases right
// after; producer p waits only on its own region. 8-deep P pipelining, halved
// producer serial work vs the 4P+8C version (which measured MfmaUtil 33%,
// pipe idle 64%, latency/convoy-bound).
__global__ __launch_bounds__(1024, 4) void k_attn(const bf16* __restrict__ kwn,
        const bf16* __restrict__ embS, const bf16* __restrict__ embT,
        const float* __restrict__ rs, float* __restrict__ Oacc,
        float* __restrict__ Lsum) {
    __shared__ __align__(16) unsigned short Qlds[64 * 512];   // 64 KB, XOR-swizzled granules
    __shared__ __align__(16) unsigned short Plds[2 * 16384];  // 64 KB: 2 slots x (64q x 256v)
    __shared__ int prod_done[2][8], cons_done[2][8];
    const int tid = threadIdx.x;
    const int s = blockIdx.x & (NSPLIT - 1), qt = blockIdx.x >> 4;
    const int q0 = qt * 64;
    const int wg = tid >> 6, lane = tid & 63, lm = lane & 15, lg = lane >> 4;

    if (tid < 16) { ((int*)prod_done)[tid] = 0; ((int*)cons_done)[tid] = 0; }
    {   // stage Q tile (64x512 bf16), granule-swizzled g' = g^(q&7)
        const uint4* src = (const uint4*)(kwn + q0 * 512);
        #pragma unroll
        for (int i = 0; i < 4; ++i) {
            const int L = (i * 1024 + tid) * 8;
            const int q = L >> 9, g = (L & 511) >> 3;
            *(uint4*)&Qlds[q * 512 + ((g ^ (q & 7)) << 3)] = src[i * 1024 + tid];
        }
    }
    __syncthreads();   // covers Q staging + flag init

    const f32x4 zero4 = {0.f, 0.f, 0.f, 0.f};
    const int c0 = (s * NCH) / NSPLIT, c1 = ((s + 1) * NCH) / NSPLIT;
    const int n = c1 - c0;

    if (wg < 8) {
        // ============ producer p: v-slice p*32, all 64 q =====================
        // swapped-operand S^T: lane holds S[q = mb*16+lm][v = p*32+nb*16+lg*4+r]
        const int p = wg;
        float lacc[4] = {0.f, 0.f, 0.f, 0.f};   // per-lane P row-sum partial, q = mb*16+lm
        for (int i = 0; i < n; ++i) {
            const int c = c0 + i;
            const int slot = i & 1, use = i >> 1;
            // rs preload (flag-independent; latency hides under S-compute)
            float4 rs4[2];
            #pragma unroll
            for (int nb = 0; nb < 2; ++nb)
                rs4[nb] = ((const float4*)(rs + c * 256 + p * 32 + nb * 16))[lg];
            // ---- S^T compute (flag-independent), distance-2 E prefetch ----
            f32x4 sacc[4][2];
            #pragma unroll
            for (int mb = 0; mb < 4; ++mb)
                #pragma unroll
                for (int nb = 0; nb < 2; ++nb) sacc[mb][nb] = zero4;
            const bf16* Eb = embS + ((size_t)(c * 16 + p * 2) * 16) * 512 + lane * 8;
            bf16x8 eb[3][2];
            #pragma unroll
            for (int nb = 0; nb < 2; ++nb) {
                eb[0][nb] = *(const bf16x8*)(Eb + (nb * 16) * 512);
                eb[1][nb] = *(const bf16x8*)(Eb + (nb * 16 + 1) * 512);
            }
            #pragma unroll
            for (int kf = 0; kf < 16; ++kf) {
                if (kf < 14) {     // distance-2 prefetch, static %3 rotation
                    #pragma unroll
                    for (int nb = 0; nb < 2; ++nb)
                        eb[(kf + 2) % 3][nb] = *(const bf16x8*)(Eb + (nb * 16 + kf + 2) * 512);
                }
                const int goff = ((kf * 4 + lg) ^ (lm & 7)) << 3;
                bf16x8 aq[4];
                #pragma unroll
                for (int mb = 0; mb < 4; ++mb)
                    aq[mb] = *(const bf16x8*)&Qlds[(mb * 16 + lm) * 512 + goff];
                __builtin_amdgcn_s_setprio(1);
                #pragma unroll
                for (int nb = 0; nb < 2; ++nb)
                    #pragma unroll
                    for (int mb = 0; mb < 4; ++mb)
                        sacc[mb][nb] = __builtin_amdgcn_mfma_f32_16x16x32_bf16(eb[kf % 3][nb], aq[mb], sacc[mb][nb], 0, 0, 0);
                __builtin_amdgcn_s_setprio(0);
                __builtin_amdgcn_sched_barrier(0);
            }
            // ---- wait OWN region free, then exp2 + contiguous packed writes ----
            while (__hip_atomic_load(&cons_done[slot][p], __ATOMIC_ACQUIRE,
                                     __HIP_MEMORY_SCOPE_WORKGROUP) < 8 * use)
                __builtin_amdgcn_s_sleep(1);
            unsigned short* Pw = Plds + (slot << 14);
            #pragma unroll
            for (int nb = 0; nb < 2; ++nb) {
                const float4 rv = rs4[nb];
                const int off = (lm + 16 * (nb * 2 + (lg >> 1))) * 8 + (lg & 1) * 4;
                #pragma unroll
                for (int mb = 0; mb < 4; ++mb) {
                    const bf16 b0 = (bf16)exp2f(sacc[mb][nb][0] * rv.x);
                    const bf16 b1 = (bf16)exp2f(sacc[mb][nb][1] * rv.y);
                    const bf16 b2 = (bf16)exp2f(sacc[mb][nb][2] * rv.z);
                    const bf16 b3 = (bf16)exp2f(sacc[mb][nb][3] * rv.w);
                    lacc[mb] += ((float)b0 + (float)b1) + ((float)b2 + (float)b3);
                    ushort4 w4;
                    w4.x = __builtin_bit_cast(unsigned short, b0);
                    w4.y = __builtin_bit_cast(unsigned short, b1);
                    w4.z = __builtin_bit_cast(unsigned short, b2);
                    w4.w = __builtin_bit_cast(unsigned short, b3);
                    *(ushort4*)&Pw[(mb * 8 + p) * 512 + off] = w4;   // conflict-free b64
                }
            }
            if (lane == 0)   // release drains LDS writes
                __hip_atomic_fetch_add(&prod_done[slot][p], 1, __ATOMIC_RELEASE,
                                       __HIP_MEMORY_SCOPE_WORKGROUP);
        }
        // Lsum: lanes sharing lm hold partials for q = mb*16+lm; reduce over lg
        #pragma unroll
        for (int mb = 0; mb < 4; ++mb) {
            float sum = lacc[mb];
            sum += __shfl_xor(sum, 16);
            sum += __shfl_xor(sum, 32);
            if (lane < 16) atomicAdd(&Lsum[q0 + mb * 16 + lm], sum);
        }
    } else {
        // ================= consumer: t-slice (wg-8)*64, all 64 q =============
        const int cw = wg - 8;
        f32x4 acc[4][4];                   // [mb 16q][nt 16t]
        #pragma unroll
        for (int mb = 0; mb < 4; ++mb)
            #pragma unroll
            for (int nt = 0; nt < 4; ++nt) acc[mb][nt] = zero4;
        for (int i = 0; i < n; ++i) {
            const int cc = c0 + i;
            const int slot = i & 1, use = i >> 1;
            const bf16* ETb = embT + ((size_t)cc * 256 + cw * 4) * 512 + lane * 8;
            // 3-buffer distance-2 E prefetch; kf=0,1 issued BEFORE any flag wait
            bf16x8 et[3][4];
            #pragma unroll
            for (int nt = 0; nt < 4; ++nt) {
                et[0][nt] = *(const bf16x8*)(ETb + nt * 512);
                et[1][nt] = *(const bf16x8*)(ETb + (32 + nt) * 512);
            }
            const unsigned short* Pb = Plds + (slot << 14);
            #pragma unroll
            for (int p = 0; p < 8; ++p) {
                if (p < 6) {       // flag-independent distance-2 prefetch
                    #pragma unroll
                    for (int nt = 0; nt < 4; ++nt)
                        et[(p + 2) % 3][nt] = *(const bf16x8*)(ETb + ((p + 2) * 32 + nt) * 512);
                }
                while (__hip_atomic_load(&prod_done[slot][p], __ATOMIC_ACQUIRE,
                                         __HIP_MEMORY_SCOPE_WORKGROUP) < use + 1)
                    __builtin_amdgcn_s_sleep(1);
                bf16x8 pf[4];
                #pragma unroll
                for (int mb = 0; mb < 4; ++mb)
                    pf[mb] = *(const bf16x8*)&Pb[(mb * 8 + p) * 512 + lane * 8];
                __builtin_amdgcn_s_setprio(1);
                #pragma unroll
                for (int nt = 0; nt < 4; ++nt)
                    #pragma unroll
                    for (int mb = 0; mb < 4; ++mb)
                        acc[mb][nt] = __builtin_amdgcn_mfma_f32_16x16x32_bf16(pf[mb], et[p % 3][nt], acc[mb][nt], 0, 0, 0);
                __builtin_amdgcn_s_setprio(0);
                if (lane == 0)   // release producer p's region (drains LDS reads)
                    __hip_atomic_fetch_add(&cons_done[slot][p], 1, __ATOMIC_RELEASE,
                                           __HIP_MEMORY_SCOPE_WORKGROUP);
            }
        }
        // epilogue: combine partials across v-splits
        #pragma unroll
        for (int mb = 0; mb < 4; ++mb)
            #pragma unroll
            for (int nt = 0; nt < 4; ++nt)
                #pragma unroll
                for (int r = 0; r < 4; ++r) {
                    const int q = q0 + mb * 16 + lg * 4 + r;
                    const int t = cw * 64 + nt * 16 + lm;
                    atomicAdd(&Oacc[q * 512 + t], acc[mb][nt][r]);
                }
    }
}

// ---------------- Kernel D: out = Oacc / Lsum --------------------------------
__global__ __launch_bounds__(256) void k_final(const float* __restrict__ Oacc,
        const float* __restrict__ Lsum, float* __restrict__ out) {
    const int i = blockIdx.x * 256 + threadIdx.x;   // float4 index, 131072 total
    const float4 o = ((const float4*)Oacc)[i];
    const float inv = 1.0f / Lsum[i >> 7];          // 128 float4 per row
    float4 r;
    r.x = o.x * inv; r.y = o.y * inv; r.z = o.z * inv; r.w = o.w * inv;
    ((float4*)out)[i] = r;
}

// ---------------- launcher ---------------------------------------------------
// ws layout (bytes) — total 104,535,040 (proven to fit):
//   0        kwn   bf16 [1024*512]          1,048,576
//   1048576  rs    f32  [49408]               197,632
//   1246208  Oacc  f32  [1024*512]          2,097,152   (zeroed each launch)
//   3343360  Lsum  f32  [1024]                   4,096   (zeroed each launch)
//   3347456  embS  bf16 frag-major          50,593,792
//   53941248 embT  bf16 frag-major          50,593,792
extern "C" void kernel_launch(void* const* d_in, const int* in_sizes, int n_in,
                              void* d_out, int out_size, void* d_ws, size_t ws_size,
                              hipStream_t stream) {
    const float* audio = (const float*)d_in[0];
    const float* W     = (const float*)d_in[1];
    const float* bias  = (const float*)d_in[2];
    const float* emb   = (const float*)d_in[3];
    float* out = (float*)d_out;
    char* ws = (char*)d_ws;

    bf16*  kwn  = (bf16*)(ws);
    float* rs   = (float*)(ws + 1048576);
    float* Oacc = (float*)(ws + 1246208);
    float* Lsum = (float*)(ws + 3343360);
    bf16*  embS = (bf16*)(ws + 3347456);
    bf16*  embT = (bf16*)(ws + 53941248);

    hipMemsetAsync(ws + 1246208, 0, 2097152 + 4096, stream);   // Oacc + Lsum
    k_proj<<<256, 256, 0, stream>>>(audio, W, bias, kwn);
    k_prep<<<VDIM / 64, 256, 0, stream>>>(emb, embS, embT, rs);
    k_attn<<<NQT * NSPLIT, 1024, 0, stream>>>(kwn, embS, embT, rs, Oacc, Lsum);
    k_final<<<(out_size / 4) / 256, 256, 0, stream>>>(Oacc, Lsum, out);
}

// Round 4
// 399.355 us; speedup vs baseline: 1.1103x; 1.1103x over previous
//
#include <hip/hip_runtime.h>
#include <math.h>

// Problem constants: B=128,N=8 -> M=1024 rows; D=768; T=512; V=49408
#define VDIM    49408
#define NCH     193          // 49408 / 256 v-chunks
#define NSPLIT  16           // V splits; s = blockIdx&15 -> all 16 WGs of split on XCD s%8
#define NQT     16           // 1024 / 64 query tiles

typedef __bf16 bf16;
typedef __bf16 bf16x8 __attribute__((ext_vector_type(8)));
typedef float  f32x4  __attribute__((ext_vector_type(4)));

// ---------------- Kernel A: kw = audio@W + b, row-normalize -> kwn (bf16) ----
__global__ __launch_bounds__(256) void k_proj(const float* __restrict__ audio,
        const float* __restrict__ W, const float* __restrict__ bias,
        bf16* __restrict__ kwn) {
    __shared__ float a_lds[4 * 768];
    __shared__ float kw_lds[4 * 512];
    __shared__ float rn_lds[4];
    const int tid = threadIdx.x;
    const int q0 = blockIdx.x * 4;

    const float4* asrc = (const float4*)(audio + q0 * 768);
    float4* adst = (float4*)a_lds;
    #pragma unroll
    for (int i = 0; i < 3; ++i) adst[i * 256 + tid] = asrc[i * 256 + tid];
    __syncthreads();

    float acc0[4] = {0.f, 0.f, 0.f, 0.f}, acc1[4] = {0.f, 0.f, 0.f, 0.f};
    #pragma unroll 4
    for (int d = 0; d < 768; ++d) {
        const float w0 = W[d * 512 + tid];
        const float w1 = W[d * 512 + 256 + tid];
        #pragma unroll
        for (int q = 0; q < 4; ++q) {
            const float a = a_lds[q * 768 + d];   // broadcast, conflict-free
            acc0[q] = fmaf(a, w0, acc0[q]);
            acc1[q] = fmaf(a, w1, acc1[q]);
        }
    }
    const float b0 = bias[tid], b1 = bias[256 + tid];
    #pragma unroll
    for (int q = 0; q < 4; ++q) {
        kw_lds[q * 512 + tid]       = acc0[q] + b0;
        kw_lds[q * 512 + 256 + tid] = acc1[q] + b1;
    }
    __syncthreads();

    const int w = tid >> 6, lane = tid & 63;
    {   // wave w handles row w
        float ss = 0.f;
        #pragma unroll
        for (int i = 0; i < 8; ++i) { const float x = kw_lds[w * 512 + lane + i * 64]; ss = fmaf(x, x, ss); }
        #pragma unroll
        for (int o = 1; o < 64; o <<= 1) ss += __shfl_xor(ss, o);
        if (lane == 0) rn_lds[w] = 1.0f / fmaxf(sqrtf(ss), 1e-8f);
    }
    __syncthreads();
    #pragma unroll
    for (int i = 0; i < 8; ++i) {
        const int idx = i * 256 + tid;
        const int q = idx >> 9;
        kwn[(q0 + q) * 512 + (idx & 511)] = (bf16)(kw_lds[idx] * rn_lds[q]);
    }
}

// ---------------- Kernel B: one-pass emb prep --------------------------------
__global__ __launch_bounds__(256) void k_prep(const float* __restrict__ emb,
        bf16* __restrict__ embS, bf16* __restrict__ embT, float* __restrict__ rs) {
    __shared__ unsigned short tile[64 * 512];
    __shared__ float pnorm[64 * 2];
    const int tid = threadIdx.x;
    const int b = blockIdx.x;
    const int v0 = b * 64;
    const int lane = tid & 63;
    const int p = (tid >> 6) & 1;          // wave parity within row

    // 1: coalesced load + fp32 norm partials + bf16 convert + swizzled LDS store
    const float4* src = (const float4*)(emb + (size_t)v0 * 512);
    #pragma unroll
    for (int i = 0; i < 32; ++i) {
        const int L = i * 256 + tid;           // float4 index in 64x128
        const int r = L >> 7, c4 = L & 127;    // whole wave shares one row r
        const float4 x = src[L];
        float ss = x.x * x.x + x.y * x.y + x.z * x.z + x.w * x.w;
        #pragma unroll
        for (int o = 1; o < 64; o <<= 1) ss += __shfl_xor(ss, o);
        if (lane == 0) pnorm[r * 2 + p] = ss;
        const int g = c4 >> 1, half = c4 & 1;
        ushort4 u;
        u.x = __builtin_bit_cast(unsigned short, (bf16)x.x);
        u.y = __builtin_bit_cast(unsigned short, (bf16)x.y);
        u.z = __builtin_bit_cast(unsigned short, (bf16)x.z);
        u.w = __builtin_bit_cast(unsigned short, (bf16)x.w);
        *(ushort4*)&tile[r * 512 + (((g ^ (r & 7)) << 3) + half * 4)] = u;
    }
    __syncthreads();
    if (tid < 64) {
        const float ss = pnorm[tid * 2] + pnorm[tid * 2 + 1];
        rs[v0 + tid] = 10.0f / fmaxf(sqrtf(ss), 1e-8f);   // folds 1/TEMP
    }

    // 2: embS frag-major (uint4 LDS reads, fully coalesced global writes)
    #pragma unroll
    for (int i = 0; i < 16; ++i) {
        const int F = i * 256 + tid;           // out granule 0..4095
        const int frag = F >> 6, l = F & 63;
        const int vt = frag >> 4, kf = frag & 15;
        const int lm = l & 15, lg = l >> 4;
        const int r = vt * 16 + lm, g = kf * 4 + lg;
        const uint4 d = *(const uint4*)&tile[r * 512 + ((g ^ (r & 7)) << 3)];
        *(uint4*)((unsigned short*)embS + ((size_t)(b * 4 + vt) * 16 + kf) * 512 + l * 8) = d;
    }
    // 3: embT frag-major (transpose gather from LDS, coalesced writes)
    #pragma unroll
    for (int i = 0; i < 16; ++i) {
        const int F = i * 256 + tid;
        const int frag = F >> 6, l = F & 63;
        const int kvl = frag >> 5, tt = frag & 31;
        const int lm = l & 15, lg = l >> 4;
        const int t = tt * 16 + lm;
        unsigned short e[8];
        #pragma unroll
        for (int j = 0; j < 8; ++j) {
            const int r = kvl * 32 + lg * 8 + j;
            e[j] = tile[r * 512 + ((((t >> 3) ^ (r & 7)) << 3) + (t & 7))];
        }
        uint4 o;
        o.x = (unsigned)e[0] | ((unsigned)e[1] << 16);
        o.y = (unsigned)e[2] | ((unsigned)e[3] << 16);
        o.z = (unsigned)e[4] | ((unsigned)e[5] << 16);
        o.w = (unsigned)e[6] | ((unsigned)e[7] << 16);
        const int kvg = b * 2 + kvl;           // global v/32 index
        *(uint4*)((unsigned short*)embT + ((size_t)kvg * 32 + tt) * 512 + l * 8) = o;
    }
}

// ---------------- Kernel C: M64 producer/consumer fused attention ------------
// 768 threads = 12 waves. Waves 0-3 (producers): S = Qn@En^T (64q x 64v slice,
// K=512) -> exp -> P-frags into 2-slot ring. Waves 4-11 (consumers): O += P@E,
// each a 64-wide t-slice. Wave-granular flag sync (lane-0 guarded, monotonic).
// This round's single concept change vs the proven 131us baseline: E-stream
// prefetch depth dist-1 -> dist-2 (3-buffer, static %3 rotation) on BOTH the
// producer embS stream (the P-critical path; covers ~600-900cy L3 latency that
// dist-1's ~310cy/iter cannot) and the consumer embT stream; plus rs loads
// hoisted off the post-wait scatter path.
__global__ __launch_bounds__(768, 3) void k_attn(const bf16* __restrict__ kwn,
        const bf16* __restrict__ embS, const bf16* __restrict__ embT,
        const float* __restrict__ rs, float* __restrict__ Oacc,
        float* __restrict__ Lsum) {
    __shared__ unsigned short Qlds[64 * 512];       // 64 KB, XOR-swizzled granules
    __shared__ unsigned short Plds[2 * 16384];      // 64 KB: 2 slots x (64q x 256v)
    __shared__ int prod_done[2], cons_done[2];
    const int tid = threadIdx.x;
    const int s = blockIdx.x & (NSPLIT - 1), qt = blockIdx.x >> 4;
    const int q0 = qt * 64;
    const int wg = tid >> 6, lane = tid & 63, lm = lane & 15, lg = lane >> 4;

    if (tid < 2) { prod_done[tid] = 0; cons_done[tid] = 0; }
    if (tid < 512) {   // stage Q tile (64x512 bf16), granule-swizzled g' = g^(q&7)
        const uint4* src = (const uint4*)(kwn + q0 * 512);
        #pragma unroll
        for (int i = 0; i < 8; ++i) {
            const int L = (i * 512 + tid) * 8;
            const int q = L >> 9, g = (L & 511) >> 3;
            *(uint4*)&Qlds[q * 512 + ((g ^ (q & 7)) << 3)] = src[i * 512 + tid];
        }
    }
    __syncthreads();   // covers Q staging + flag init

    const f32x4 zero4 = {0.f, 0.f, 0.f, 0.f};
    const int c0 = (s * NCH) / NSPLIT, c1 = ((s + 1) * NCH) / NSPLIT;
    const int n = c1 - c0;

    if (wg < 4) {
        // ================= producer: v-slice wg*64, all 64 q =================
        float lacc[4][4];
        #pragma unroll
        for (int mb = 0; mb < 4; ++mb)
            #pragma unroll
            for (int r = 0; r < 4; ++r) lacc[mb][r] = 0.f;
        for (int i = 0; i < n; ++i) {
            const int c = c0 + i;
            const int slot = i & 1, use = i >> 1;
            // rs preload: off the post-wait critical path (flag-independent)
            float rsv4[4];
            #pragma unroll
            for (int nb = 0; nb < 4; ++nb)
                rsv4[nb] = rs[c * 256 + wg * 64 + nb * 16 + lm];
            // ---- S compute (flag-independent), distance-2 3-buffer E stream ----
            f32x4 sacc[4][4];
            #pragma unroll
            for (int mb = 0; mb < 4; ++mb)
                #pragma unroll
                for (int nb = 0; nb < 4; ++nb) sacc[mb][nb] = zero4;
            const bf16* Eb = embS + ((size_t)(c * 16 + wg * 4) * 16) * 512 + lane * 8;
            bf16x8 eb[3][4];
            #pragma unroll
            for (int nb = 0; nb < 4; ++nb) {
                eb[0][nb] = *(const bf16x8*)(Eb + (nb * 16) * 512);
                eb[1][nb] = *(const bf16x8*)(Eb + (nb * 16 + 1) * 512);
            }
            #pragma unroll
            for (int kf = 0; kf < 16; ++kf) {
                if (kf < 14) {     // distance-2 prefetch, static %3 rotation
                    #pragma unroll
                    for (int nb = 0; nb < 4; ++nb)
                        eb[(kf + 2) % 3][nb] = *(const bf16x8*)(Eb + (nb * 16 + kf + 2) * 512);
                }
                const int goff = ((kf * 4 + lg) ^ (lm & 7)) << 3;
                bf16x8 aq[4];
                #pragma unroll
                for (int mb = 0; mb < 4; ++mb)
                    aq[mb] = *(const bf16x8*)&Qlds[(mb * 16 + lm) * 512 + goff];
                #pragma unroll
                for (int nb = 0; nb < 4; ++nb)
                    #pragma unroll
                    for (int mb = 0; mb < 4; ++mb)
                        sacc[mb][nb] = __builtin_amdgcn_mfma_f32_16x16x32_bf16(aq[mb], eb[kf % 3][nb], sacc[mb][nb], 0, 0, 0);
                __builtin_amdgcn_sched_barrier(0);
            }
            // ---- wait slot free (8 consumers), then exp + scatter ----
            while (__hip_atomic_load(&cons_done[slot], __ATOMIC_ACQUIRE,
                                     __HIP_MEMORY_SCOPE_WORKGROUP) < 8 * use)
                __builtin_amdgcn_s_sleep(1);
            unsigned short* Pw = Plds + (slot << 14);
            #pragma unroll
            for (int nb = 0; nb < 4; ++nb) {
                const float rsv = rsv4[nb];
                const int kv = 2 * wg + (nb >> 1);
                const int lA = ((nb & 1) * 2 + (lm >> 3)) * 16;
                const int jj = lm & 7;
                #pragma unroll
                for (int mb = 0; mb < 4; ++mb) {
                    const int fragbase = (mb * 8 + kv) * 512;
                    #pragma unroll
                    for (int r = 0; r < 4; ++r) {
                        const float pv = __expf(sacc[mb][nb][r] * rsv);
                        const bf16 pb = (bf16)pv;
                        lacc[mb][r] += (float)pb;   // rounded value for consistency
                        const int ldest = lA + lg * 4 + r;
                        Pw[fragbase + ldest * 8 + jj] = __builtin_bit_cast(unsigned short, pb);
                    }
                }
            }
            if (lane == 0)   // ONE increment per wave (release drains LDS writes)
                __hip_atomic_fetch_add(&prod_done[slot], 1, __ATOMIC_RELEASE,
                                       __HIP_MEMORY_SCOPE_WORKGROUP);
        }
        // Lsum: partial over this wave's v-slices, one atomic per q at the end
        #pragma unroll
        for (int mb = 0; mb < 4; ++mb)
            #pragma unroll
            for (int r = 0; r < 4; ++r) {
                float sum = lacc[mb][r];
                sum += __shfl_xor(sum, 1);
                sum += __shfl_xor(sum, 2);
                sum += __shfl_xor(sum, 4);
                sum += __shfl_xor(sum, 8);
                if (lm == 0) atomicAdd(&Lsum[q0 + mb * 16 + lg * 4 + r], sum);
            }
    } else {
        // ================= consumer: t-slice (wg-4)*64, all 64 q =============
        const int cw = wg - 4;
        f32x4 acc[4][4];                   // [mb 16q][nt 16t]
        #pragma unroll
        for (int mb = 0; mb < 4; ++mb)
            #pragma unroll
            for (int nt = 0; nt < 4; ++nt) acc[mb][nt] = zero4;
        for (int i = 0; i < n; ++i) {
            const int cc = c0 + i;
            const int slot = i & 1, use = i >> 1;
            const bf16* ETb = embT + ((size_t)cc * 256 + cw * 4) * 512 + lane * 8;
            // distance-2 3-buffer ET stream; kf=0,1 issued BEFORE the flag wait
            bf16x8 et[3][4];
            #pragma unroll
            for (int nt = 0; nt < 4; ++nt) {
                et[0][nt] = *(const bf16x8*)(ETb + nt * 512);
                et[1][nt] = *(const bf16x8*)(ETb + (32 + nt) * 512);
            }
            while (__hip_atomic_load(&prod_done[slot], __ATOMIC_ACQUIRE,
                                     __HIP_MEMORY_SCOPE_WORKGROUP) < 4 * (use + 1))
                __builtin_amdgcn_s_sleep(1);
            const unsigned short* Pb = Plds + (slot << 14);
            #pragma unroll
            for (int kf = 0; kf < 8; ++kf) {
                if (kf < 6) {      // distance-2 prefetch, static %3 rotation
                    #pragma unroll
                    for (int nt = 0; nt < 4; ++nt)
                        et[(kf + 2) % 3][nt] = *(const bf16x8*)(ETb + ((kf + 2) * 32 + nt) * 512);
                }
                bf16x8 pf[4];
                #pragma unroll
                for (int mb = 0; mb < 4; ++mb)
                    pf[mb] = *(const bf16x8*)&Pb[(mb * 8 + kf) * 512 + lane * 8];
                #pragma unroll
                for (int nt = 0; nt < 4; ++nt)
                    #pragma unroll
                    for (int mb = 0; mb < 4; ++mb)
                        acc[mb][nt] = __builtin_amdgcn_mfma_f32_16x16x32_bf16(pf[mb], et[kf % 3][nt], acc[mb][nt], 0, 0, 0);
                __builtin_amdgcn_sched_barrier(0);
            }
            if (lane == 0)   // ONE increment per wave (release drains LDS reads)
                __hip_atomic_fetch_add(&cons_done[slot], 1, __ATOMIC_RELEASE,
                                       __HIP_MEMORY_SCOPE_WORKGROUP);
        }
        // epilogue: combine partials across v-splits
        #pragma unroll
        for (int mb = 0; mb < 4; ++mb)
            #pragma unroll
            for (int nt = 0; nt < 4; ++nt)
                #pragma unroll
                for (int r = 0; r < 4; ++r) {
                    const int q = q0 + mb * 16 + lg * 4 + r;
                    const int t = cw * 64 + nt * 16 + lm;
                    atomicAdd(&Oacc[q * 512 + t], acc[mb][nt][r]);
                }
    }
}

// ---------------- Kernel D: out = Oacc / Lsum --------------------------------
__global__ __launch_bounds__(256) void k_final(const float* __restrict__ Oacc,
        const float* __restrict__ Lsum, float* __restrict__ out) {
    const int i = blockIdx.x * 256 + threadIdx.x;   // float4 index, 131072 total
    const float4 o = ((const float4*)Oacc)[i];
    const float inv = 1.0f / Lsum[i >> 7];          // 128 float4 per row
    float4 r;
    r.x = o.x * inv; r.y = o.y * inv; r.z = o.z * inv; r.w = o.w * inv;
    ((float4*)out)[i] = r;
}

// ---------------- launcher ---------------------------------------------------
// ws layout (bytes) — total 104,535,040 (proven to fit):
//   0        kwn   bf16 [1024*512]          1,048,576
//   1048576  rs    f32  [49408]               197,632
//   1246208  Oacc  f32  [1024*512]          2,097,152   (zeroed each launch)
//   3343360  Lsum  f32  [1024]                   4,096   (zeroed each launch)
//   3347456  embS  bf16 frag-major          50,593,792
//   53941248 embT  bf16 frag-major          50,593,792
extern "C" void kernel_launch(void* const* d_in, const int* in_sizes, int n_in,
                              void* d_out, int out_size, void* d_ws, size_t ws_size,
                              hipStream_t stream) {
    const float* audio = (const float*)d_in[0];
    const float* W     = (const float*)d_in[1];
    const float* bias  = (const float*)d_in[2];
    const float* emb   = (const float*)d_in[3];
    float* out = (float*)d_out;
    char* ws = (char*)d_ws;

    bf16*  kwn  = (bf16*)(ws);
    float* rs   = (float*)(ws + 1048576);
    float* Oacc = (float*)(ws + 1246208);
    float* Lsum = (float*)(ws + 3343360);
    bf16*  embS = (bf16*)(ws + 3347456);
    bf16*  embT = (bf16*)(ws + 53941248);

    hipMemsetAsync(ws + 1246208, 0, 2097152 + 4096, stream);   // Oacc + Lsum
    k_proj<<<256, 256, 0, stream>>>(audio, W, bias, kwn);
    k_prep<<<VDIM / 64, 256, 0, stream>>>(emb, embS, embT, rs);
    k_attn<<<NQT * NSPLIT, 768, 0, stream>>>(kwn, embS, embT, rs, Oacc, Lsum);
    k_final<<<(out_size / 4) / 256, 256, 0, stream>>>(Oacc, Lsum, out);
}

// Round 5
// 391.292 us; speedup vs baseline: 1.1332x; 1.0206x over previous
//
#include <hip/hip_runtime.h>
#include <math.h>

// Problem constants: B=128,N=8 -> M=1024 rows; D=768; T=512; V=49408
#define VDIM    49408
#define NCH     193          // 49408 / 256 v-chunks
#define NSPLIT  16           // V splits; s = blockIdx&15 -> all 16 WGs of split on XCD s%8
#define NQT     16           // 1024 / 64 query tiles
#define NPREP   772          // VDIM/64 prep blocks; proj blocks follow

typedef __bf16 bf16;
typedef __bf16 bf16x8 __attribute__((ext_vector_type(8)));
typedef float  f32x4  __attribute__((ext_vector_type(4)));

// ---------------- Kernel AB (fused): prep (772 blocks) + proj (256 blocks) ---
// Fusing kills 2 graph nodes (memset + separate proj) and gives proj's
// latency-bound W-loop co-resident prep waves to hide L2 latency under.
// proj blocks also zero Oacc+Lsum (2101248 B = 131328 float4, 513 per block).
__global__ __launch_bounds__(256) void k_pre(const float* __restrict__ emb,
        bf16* __restrict__ embS, bf16* __restrict__ embT, float* __restrict__ rs,
        const float* __restrict__ audio, const float* __restrict__ W,
        const float* __restrict__ bias, bf16* __restrict__ kwn,
        float4* __restrict__ zbase) {
    __shared__ __align__(16) unsigned char smem[64 * 512 * 2 + 64 * 2 * 4];
    const int tid = threadIdx.x;
    const int lane = tid & 63;

    if (blockIdx.x < NPREP) {
        // ===================== prep branch (one-pass emb prep) ==============
        unsigned short* tile = (unsigned short*)smem;          // 64x512 bf16
        float* pnorm = (float*)(smem + 64 * 512 * 2);          // 64x2
        const int b = blockIdx.x;
        const int v0 = b * 64;
        const int p = (tid >> 6) & 1;      // wave parity within row

        // 1: coalesced load + fp32 norm partials + bf16 convert + swizzled LDS
        const float4* src = (const float4*)(emb + (size_t)v0 * 512);
        #pragma unroll
        for (int i = 0; i < 32; ++i) {
            const int L = i * 256 + tid;           // float4 index in 64x128
            const int r = L >> 7, c4 = L & 127;    // whole wave shares one row r
            const float4 x = src[L];
            float ss = x.x * x.x + x.y * x.y + x.z * x.z + x.w * x.w;
            #pragma unroll
            for (int o = 1; o < 64; o <<= 1) ss += __shfl_xor(ss, o);
            if (lane == 0) pnorm[r * 2 + p] = ss;
            const int g = c4 >> 1, half = c4 & 1;
            ushort4 u;
            u.x = __builtin_bit_cast(unsigned short, (bf16)x.x);
            u.y = __builtin_bit_cast(unsigned short, (bf16)x.y);
            u.z = __builtin_bit_cast(unsigned short, (bf16)x.z);
            u.w = __builtin_bit_cast(unsigned short, (bf16)x.w);
            *(ushort4*)&tile[r * 512 + (((g ^ (r & 7)) << 3) + half * 4)] = u;
        }
        __syncthreads();
        if (tid < 64) {
            const float ss = pnorm[tid * 2] + pnorm[tid * 2 + 1];
            rs[v0 + tid] = 10.0f / fmaxf(sqrtf(ss), 1e-8f);   // folds 1/TEMP
        }

        // 2: embS frag-major (uint4 LDS reads, coalesced global writes)
        #pragma unroll
        for (int i = 0; i < 16; ++i) {
            const int F = i * 256 + tid;           // out granule 0..4095
            const int frag = F >> 6, l = F & 63;
            const int vt = frag >> 4, kf = frag & 15;
            const int lm = l & 15, lg = l >> 4;
            const int r = vt * 16 + lm, g = kf * 4 + lg;
            const uint4 d = *(const uint4*)&tile[r * 512 + ((g ^ (r & 7)) << 3)];
            *(uint4*)((unsigned short*)embS + ((size_t)(b * 4 + vt) * 16 + kf) * 512 + l * 8) = d;
        }
        // 3: embT frag-major (transpose gather from LDS, coalesced writes)
        #pragma unroll
        for (int i = 0; i < 16; ++i) {
            const int F = i * 256 + tid;
            const int frag = F >> 6, l = F & 63;
            const int kvl = frag >> 5, tt = frag & 31;
            const int lm = l & 15, lg = l >> 4;
            const int t = tt * 16 + lm;
            unsigned short e[8];
            #pragma unroll
            for (int j = 0; j < 8; ++j) {
                const int r = kvl * 32 + lg * 8 + j;
                e[j] = tile[r * 512 + ((((t >> 3) ^ (r & 7)) << 3) + (t & 7))];
            }
            uint4 o;
            o.x = (unsigned)e[0] | ((unsigned)e[1] << 16);
            o.y = (unsigned)e[2] | ((unsigned)e[3] << 16);
            o.z = (unsigned)e[4] | ((unsigned)e[5] << 16);
            o.w = (unsigned)e[6] | ((unsigned)e[7] << 16);
            const int kvg = b * 2 + kvl;           // global v/32 index
            *(uint4*)((unsigned short*)embT + ((size_t)kvg * 32 + tt) * 512 + l * 8) = o;
        }
    } else {
        // ===================== proj branch (kw = audio@W + b, normalize) ====
        float* a_lds  = (float*)smem;                  // 4*768
        float* kw_lds = (float*)(smem + 12288);        // 4*512
        float* rn_lds = (float*)(smem + 20480);        // 4
        const int pb = blockIdx.x - NPREP;
        const int q0 = pb * 4;

        // zero Oacc+Lsum slice (replaces hipMemsetAsync node): 513 float4/block
        for (int j = tid; j < 513; j += 256) zbase[pb * 513 + j] = float4{0.f, 0.f, 0.f, 0.f};

        const float4* asrc = (const float4*)(audio + q0 * 768);
        float4* adst = (float4*)a_lds;
        #pragma unroll
        for (int i = 0; i < 3; ++i) adst[i * 256 + tid] = asrc[i * 256 + tid];
        __syncthreads();

        float acc0[4] = {0.f, 0.f, 0.f, 0.f}, acc1[4] = {0.f, 0.f, 0.f, 0.f};
        #pragma unroll 4
        for (int d = 0; d < 768; ++d) {
            const float w0 = W[d * 512 + tid];
            const float w1 = W[d * 512 + 256 + tid];
            #pragma unroll
            for (int q = 0; q < 4; ++q) {
                const float a = a_lds[q * 768 + d];   // broadcast, conflict-free
                acc0[q] = fmaf(a, w0, acc0[q]);
                acc1[q] = fmaf(a, w1, acc1[q]);
            }
        }
        const float b0 = bias[tid], b1 = bias[256 + tid];
        #pragma unroll
        for (int q = 0; q < 4; ++q) {
            kw_lds[q * 512 + tid]       = acc0[q] + b0;
            kw_lds[q * 512 + 256 + tid] = acc1[q] + b1;
        }
        __syncthreads();

        const int w = tid >> 6;
        {   // wave w handles row w
            float ss = 0.f;
            #pragma unroll
            for (int i = 0; i < 8; ++i) { const float x = kw_lds[w * 512 + lane + i * 64]; ss = fmaf(x, x, ss); }
            #pragma unroll
            for (int o = 1; o < 64; o <<= 1) ss += __shfl_xor(ss, o);
            if (lane == 0) rn_lds[w] = 1.0f / fmaxf(sqrtf(ss), 1e-8f);
        }
        __syncthreads();
        #pragma unroll
        for (int i = 0; i < 8; ++i) {
            const int idx = i * 256 + tid;
            const int q = idx >> 9;
            kwn[(q0 + q) * 512 + (idx & 511)] = (bf16)(kw_lds[idx] * rn_lds[q]);
        }
    }
}

// ---------------- Kernel C: M64 producer/consumer fused attention ------------
// 768 threads = 12 waves. Waves 0-3 (producers): S = Qn@En^T (64q x 64v slice,
// K=512) -> exp -> P-frags into 2-slot ring. Waves 4-11 (consumers): O += P@E,
// each a 64-wide t-slice. Wave-granular flag sync. dist-2 3-buffer E streams
// both sides (proven +14us). This round: (a) producer-ONLY setprio(1) around
// the S MFMA cluster and exp/scatter (critical-path wave wins SIMD arbitration
// vs slack-rich consumers), (b) consumer releases the P slot right after the
// LAST kf's P-fragment loads (RELEASE drains LDS reads; the trailing MFMAs are
// register-only) -> slot free ~310cy earlier per chunk.
__global__ __launch_bounds__(768, 3) void k_attn(const bf16* __restrict__ kwn,
        const bf16* __restrict__ embS, const bf16* __restrict__ embT,
        const float* __restrict__ rs, float* __restrict__ Oacc,
        float* __restrict__ Lsum) {
    __shared__ unsigned short Qlds[64 * 512];       // 64 KB, XOR-swizzled granules
    __shared__ unsigned short Plds[2 * 16384];      // 64 KB: 2 slots x (64q x 256v)
    __shared__ int prod_done[2], cons_done[2];
    const int tid = threadIdx.x;
    const int s = blockIdx.x & (NSPLIT - 1), qt = blockIdx.x >> 4;
    const int q0 = qt * 64;
    const int wg = tid >> 6, lane = tid & 63, lm = lane & 15, lg = lane >> 4;

    if (tid < 2) { prod_done[tid] = 0; cons_done[tid] = 0; }
    if (tid < 512) {   // stage Q tile (64x512 bf16), granule-swizzled g' = g^(q&7)
        const uint4* src = (const uint4*)(kwn + q0 * 512);
        #pragma unroll
        for (int i = 0; i < 8; ++i) {
            const int L = (i * 512 + tid) * 8;
            const int q = L >> 9, g = (L & 511) >> 3;
            *(uint4*)&Qlds[q * 512 + ((g ^ (q & 7)) << 3)] = src[i * 512 + tid];
        }
    }
    __syncthreads();   // covers Q staging + flag init

    const f32x4 zero4 = {0.f, 0.f, 0.f, 0.f};
    const int c0 = (s * NCH) / NSPLIT, c1 = ((s + 1) * NCH) / NSPLIT;
    const int n = c1 - c0;

    if (wg < 4) {
        // ================= producer: v-slice wg*64, all 64 q =================
        float lacc[4][4];
        #pragma unroll
        for (int mb = 0; mb < 4; ++mb)
            #pragma unroll
            for (int r = 0; r < 4; ++r) lacc[mb][r] = 0.f;
        for (int i = 0; i < n; ++i) {
            const int c = c0 + i;
            const int slot = i & 1, use = i >> 1;
            // rs preload: off the post-wait critical path (flag-independent)
            float rsv4[4];
            #pragma unroll
            for (int nb = 0; nb < 4; ++nb)
                rsv4[nb] = rs[c * 256 + wg * 64 + nb * 16 + lm];
            // ---- S compute (flag-independent), distance-2 3-buffer E stream ----
            f32x4 sacc[4][4];
            #pragma unroll
            for (int mb = 0; mb < 4; ++mb)
                #pragma unroll
                for (int nb = 0; nb < 4; ++nb) sacc[mb][nb] = zero4;
            const bf16* Eb = embS + ((size_t)(c * 16 + wg * 4) * 16) * 512 + lane * 8;
            bf16x8 eb[3][4];
            #pragma unroll
            for (int nb = 0; nb < 4; ++nb) {
                eb[0][nb] = *(const bf16x8*)(Eb + (nb * 16) * 512);
                eb[1][nb] = *(const bf16x8*)(Eb + (nb * 16 + 1) * 512);
            }
            #pragma unroll
            for (int kf = 0; kf < 16; ++kf) {
                if (kf < 14) {     // distance-2 prefetch, static %3 rotation
                    #pragma unroll
                    for (int nb = 0; nb < 4; ++nb)
                        eb[(kf + 2) % 3][nb] = *(const bf16x8*)(Eb + (nb * 16 + kf + 2) * 512);
                }
                const int goff = ((kf * 4 + lg) ^ (lm & 7)) << 3;
                bf16x8 aq[4];
                #pragma unroll
                for (int mb = 0; mb < 4; ++mb)
                    aq[mb] = *(const bf16x8*)&Qlds[(mb * 16 + lm) * 512 + goff];
                __builtin_amdgcn_s_setprio(1);   // producer = P critical path
                #pragma unroll
                for (int nb = 0; nb < 4; ++nb)
                    #pragma unroll
                    for (int mb = 0; mb < 4; ++mb)
                        sacc[mb][nb] = __builtin_amdgcn_mfma_f32_16x16x32_bf16(aq[mb], eb[kf % 3][nb], sacc[mb][nb], 0, 0, 0);
                __builtin_amdgcn_s_setprio(0);
                __builtin_amdgcn_sched_barrier(0);
            }
            // ---- wait slot free (8 consumers), then exp + scatter ----
            while (__hip_atomic_load(&cons_done[slot], __ATOMIC_ACQUIRE,
                                     __HIP_MEMORY_SCOPE_WORKGROUP) < 8 * use)
                __builtin_amdgcn_s_sleep(1);
            unsigned short* Pw = Plds + (slot << 14);
            __builtin_amdgcn_s_setprio(1);       // scatter is also critical path
            #pragma unroll
            for (int nb = 0; nb < 4; ++nb) {
                const float rsv = rsv4[nb];
                const int kv = 2 * wg + (nb >> 1);
                const int lA = ((nb & 1) * 2 + (lm >> 3)) * 16;
                const int jj = lm & 7;
                #pragma unroll
                for (int mb = 0; mb < 4; ++mb) {
                    const int fragbase = (mb * 8 + kv) * 512;
                    #pragma unroll
                    for (int r = 0; r < 4; ++r) {
                        const float pv = __expf(sacc[mb][nb][r] * rsv);
                        const bf16 pb = (bf16)pv;
                        lacc[mb][r] += (float)pb;   // rounded value for consistency
                        const int ldest = lA + lg * 4 + r;
                        Pw[fragbase + ldest * 8 + jj] = __builtin_bit_cast(unsigned short, pb);
                    }
                }
            }
            __builtin_amdgcn_s_setprio(0);
            if (lane == 0)   // ONE increment per wave (release drains LDS writes)
                __hip_atomic_fetch_add(&prod_done[slot], 1, __ATOMIC_RELEASE,
                                       __HIP_MEMORY_SCOPE_WORKGROUP);
        }
        // Lsum: partial over this wave's v-slices, one atomic per q at the end
        #pragma unroll
        for (int mb = 0; mb < 4; ++mb)
            #pragma unroll
            for (int r = 0; r < 4; ++r) {
                float sum = lacc[mb][r];
                sum += __shfl_xor(sum, 1);
                sum += __shfl_xor(sum, 2);
                sum += __shfl_xor(sum, 4);
                sum += __shfl_xor(sum, 8);
                if (lm == 0) atomicAdd(&Lsum[q0 + mb * 16 + lg * 4 + r], sum);
            }
    } else {
        // ================= consumer: t-slice (wg-4)*64, all 64 q =============
        const int cw = wg - 4;
        f32x4 acc[4][4];                   // [mb 16q][nt 16t]
        #pragma unroll
        for (int mb = 0; mb < 4; ++mb)
            #pragma unroll
            for (int nt = 0; nt < 4; ++nt) acc[mb][nt] = zero4;
        for (int i = 0; i < n; ++i) {
            const int cc = c0 + i;
            const int slot = i & 1, use = i >> 1;
            const bf16* ETb = embT + ((size_t)cc * 256 + cw * 4) * 512 + lane * 8;
            // distance-2 3-buffer ET stream; kf=0,1 issued BEFORE the flag wait
            bf16x8 et[3][4];
            #pragma unroll
            for (int nt = 0; nt < 4; ++nt) {
                et[0][nt] = *(const bf16x8*)(ETb + nt * 512);
                et[1][nt] = *(const bf16x8*)(ETb + (32 + nt) * 512);
            }
            while (__hip_atomic_load(&prod_done[slot], __ATOMIC_ACQUIRE,
                                     __HIP_MEMORY_SCOPE_WORKGROUP) < 4 * (use + 1))
                __builtin_amdgcn_s_sleep(1);
            const unsigned short* Pb = Plds + (slot << 14);
            #pragma unroll
            for (int kf = 0; kf < 8; ++kf) {
                if (kf < 6) {      // distance-2 prefetch, static %3 rotation
                    #pragma unroll
                    for (int nt = 0; nt < 4; ++nt)
                        et[(kf + 2) % 3][nt] = *(const bf16x8*)(ETb + ((kf + 2) * 32 + nt) * 512);
                }
                bf16x8 pf[4];
                #pragma unroll
                for (int mb = 0; mb < 4; ++mb)
                    pf[mb] = *(const bf16x8*)&Pb[(mb * 8 + kf) * 512 + lane * 8];
                // early slot release: P regs loaded; trailing MFMAs are
                // register-only. RELEASE orders the LDS reads above.
                if (kf == 7 && lane == 0)
                    __hip_atomic_fetch_add(&cons_done[slot], 1, __ATOMIC_RELEASE,
                                           __HIP_MEMORY_SCOPE_WORKGROUP);
                #pragma unroll
                for (int nt = 0; nt < 4; ++nt)
                    #pragma unroll
                    for (int mb = 0; mb < 4; ++mb)
                        acc[mb][nt] = __builtin_amdgcn_mfma_f32_16x16x32_bf16(pf[mb], et[kf % 3][nt], acc[mb][nt], 0, 0, 0);
                __builtin_amdgcn_sched_barrier(0);
            }
        }
        // epilogue: combine partials across v-splits
        #pragma unroll
        for (int mb = 0; mb < 4; ++mb)
            #pragma unroll
            for (int nt = 0; nt < 4; ++nt)
                #pragma unroll
                for (int r = 0; r < 4; ++r) {
                    const int q = q0 + mb * 16 + lg * 4 + r;
                    const int t = cw * 64 + nt * 16 + lm;
                    atomicAdd(&Oacc[q * 512 + t], acc[mb][nt][r]);
                }
    }
}

// ---------------- Kernel D: out = Oacc / Lsum --------------------------------
__global__ __launch_bounds__(256) void k_final(const float* __restrict__ Oacc,
        const float* __restrict__ Lsum, float* __restrict__ out) {
    const int i = blockIdx.x * 256 + threadIdx.x;   // float4 index, 131072 total
    const float4 o = ((const float4*)Oacc)[i];
    const float inv = 1.0f / Lsum[i >> 7];          // 128 float4 per row
    float4 r;
    r.x = o.x * inv; r.y = o.y * inv; r.z = o.z * inv; r.w = o.w * inv;
    ((float4*)out)[i] = r;
}

// ---------------- launcher ---------------------------------------------------
// ws layout (bytes) — total 104,535,040 (proven to fit):
//   0        kwn   bf16 [1024*512]          1,048,576
//   1048576  rs    f32  [49408]               197,632
//   1246208  Oacc  f32  [1024*512]          2,097,152   (zeroed by k_pre proj blocks)
//   3343360  Lsum  f32  [1024]                   4,096   (zeroed by k_pre proj blocks)
//   3347456  embS  bf16 frag-major          50,593,792
//   53941248 embT  bf16 frag-major          50,593,792
extern "C" void kernel_launch(void* const* d_in, const int* in_sizes, int n_in,
                              void* d_out, int out_size, void* d_ws, size_t ws_size,
                              hipStream_t stream) {
    const float* audio = (const float*)d_in[0];
    const float* W     = (const float*)d_in[1];
    const float* bias  = (const float*)d_in[2];
    const float* emb   = (const float*)d_in[3];
    float* out = (float*)d_out;
    char* ws = (char*)d_ws;

    bf16*  kwn  = (bf16*)(ws);
    float* rs   = (float*)(ws + 1048576);
    float* Oacc = (float*)(ws + 1246208);
    float* Lsum = (float*)(ws + 3343360);
    bf16*  embS = (bf16*)(ws + 3347456);
    bf16*  embT = (bf16*)(ws + 53941248);
    float4* zbase = (float4*)(ws + 1246208);        // Oacc+Lsum contiguous, 131328 float4

    k_pre<<<NPREP + 256, 256, 0, stream>>>(emb, embS, embT, rs, audio, W, bias, kwn, zbase);
    k_attn<<<NQT * NSPLIT, 768, 0, stream>>>(kwn, embS, embT, rs, Oacc, Lsum);
    k_final<<<(out_size / 4) / 256, 256, 0, stream>>>(Oacc, Lsum, out);
}

// Round 8
// 379.093 us; speedup vs baseline: 1.1697x; 1.0322x over previous
//
#include <hip/hip_runtime.h>
#include <math.h>

// Problem constants: B=128,N=8 -> M=1024 rows; D=768; T=512; V=49408
#define VDIM    49408
#define NCH     193          // 49408 / 256 v-chunks
#define NSPLIT  16           // V splits; s = blockIdx&15 -> all 16 WGs of split on XCD s%8
#define NQT     16           // 1024 / 64 query tiles
#define NPROJ   256          // proj blocks FIRST (latency-bound, runs in prep's shadow)
#define NPREPB  1544         // VDIM/32 prep blocks (32-row tiles)

typedef __bf16 bf16;
typedef __bf16 bf16x8 __attribute__((ext_vector_type(8)));
typedef float  f32x4  __attribute__((ext_vector_type(4)));

// ---------------- Kernel AB (fused): proj (256 blocks) + prep (1544 blocks) --
// Round-6 prep restructure: 32-row tiles (33KB LDS -> 4 blocks/CU vs 2) and
// batched phase-1 loads (8 float4 into regs, then process) to deepen MLP.
// Round-5 measured k_pre at 159us, 1.03TB/s (13% HBM), Occ 16%: LDS-capped
// 2 blocks/CU x shallow outstanding-load depth (load->12-op shfl chain serial)
// starved HBM. proj blocks first so their latency-bound W-loop overlaps prep.
__global__ __launch_bounds__(256) void k_pre(const float* __restrict__ emb,
        bf16* __restrict__ embS, bf16* __restrict__ embT, float* __restrict__ rs,
        const float* __restrict__ audio, const float* __restrict__ W,
        const float* __restrict__ bias, bf16* __restrict__ kwn,
        float4* __restrict__ zbase) {
    __shared__ __align__(16) unsigned char smem[32 * 512 * 2 + 32 * 2 * 4];
    const int tid = threadIdx.x;
    const int lane = tid & 63;

    if (blockIdx.x >= NPROJ) {
        // ===================== prep branch: 32-row tile =====================
        unsigned short* tile = (unsigned short*)smem;          // 32x512 bf16
        float* pnorm = (float*)(smem + 32 * 512 * 2);          // 32x2
        const int b = blockIdx.x - NPROJ;
        const int v0 = b * 32;
        const int p = (tid >> 6) & 1;      // wave parity within row

        // 1: batched coalesced load (8 float4 in flight) + fp32 norm partials
        //    + bf16 convert + swizzled LDS store. 16 iters = 2 batches of 8.
        const float4* src = (const float4*)(emb + (size_t)v0 * 512);
        #pragma unroll
        for (int ii = 0; ii < 2; ++ii) {
            float4 xb[8];
            #pragma unroll
            for (int j = 0; j < 8; ++j) xb[j] = src[(ii * 8 + j) * 256 + tid];
            #pragma unroll
            for (int j = 0; j < 8; ++j) {
                const int L = (ii * 8 + j) * 256 + tid;   // float4 idx in 32x128
                const int r = L >> 7, c4 = L & 127;       // wave shares one row r
                const float4 x = xb[j];
                float ss = x.x * x.x + x.y * x.y + x.z * x.z + x.w * x.w;
                #pragma unroll
                for (int o = 1; o < 64; o <<= 1) ss += __shfl_xor(ss, o);
                if (lane == 0) pnorm[r * 2 + p] = ss;
                const int g = c4 >> 1, half = c4 & 1;
                ushort4 u;
                u.x = __builtin_bit_cast(unsigned short, (bf16)x.x);
                u.y = __builtin_bit_cast(unsigned short, (bf16)x.y);
                u.z = __builtin_bit_cast(unsigned short, (bf16)x.z);
                u.w = __builtin_bit_cast(unsigned short, (bf16)x.w);
                *(ushort4*)&tile[r * 512 + (((g ^ (r & 7)) << 3) + half * 4)] = u;
            }
        }
        __syncthreads();
        if (tid < 32) {
            const float ss = pnorm[tid * 2] + pnorm[tid * 2 + 1];
            rs[v0 + tid] = 10.0f / fmaxf(sqrtf(ss), 1e-8f);   // folds 1/TEMP
        }

        // 2: embS frag-major (uint4 LDS reads, coalesced global writes), 8 iters
        #pragma unroll
        for (int i = 0; i < 8; ++i) {
            const int F = i * 256 + tid;           // out granule 0..2047
            const int frag = F >> 6, l = F & 63;
            const int vt = frag >> 4, kf = frag & 15;   // vt 0..1
            const int lm = l & 15, lg = l >> 4;
            const int r = vt * 16 + lm, g = kf * 4 + lg;
            const uint4 d = *(const uint4*)&tile[r * 512 + ((g ^ (r & 7)) << 3)];
            *(uint4*)((unsigned short*)embS + ((size_t)(b * 2 + vt) * 16 + kf) * 512 + l * 8) = d;
        }
        // 3: embT frag-major (transpose gather from LDS, coalesced writes), 8 iters
        #pragma unroll
        for (int i = 0; i < 8; ++i) {
            const int F = i * 256 + tid;
            const int tt = F >> 6, l = F & 63;     // tt 0..31, kvl == 0
            const int lm = l & 15, lg = l >> 4;
            const int t = tt * 16 + lm;
            unsigned short e[8];
            #pragma unroll
            for (int j = 0; j < 8; ++j) {
                const int r = lg * 8 + j;          // 0..31
                e[j] = tile[r * 512 + ((((t >> 3) ^ (r & 7)) << 3) + (t & 7))];
            }
            uint4 o;
            o.x = (unsigned)e[0] | ((unsigned)e[1] << 16);
            o.y = (unsigned)e[2] | ((unsigned)e[3] << 16);
            o.z = (unsigned)e[4] | ((unsigned)e[5] << 16);
            o.w = (unsigned)e[6] | ((unsigned)e[7] << 16);
            // global v/32 index == b; frag index = b*32 + tt (layout unchanged)
            *(uint4*)((unsigned short*)embT + ((size_t)b * 32 + tt) * 512 + l * 8) = o;
        }
    } else {
        // ===================== proj branch (kw = audio@W + b, normalize) ====
        float* a_lds  = (float*)smem;                  // 4*768
        float* kw_lds = (float*)(smem + 12288);        // 4*512
        float* rn_lds = (float*)(smem + 20480);        // 4
        const int pb = blockIdx.x;
        const int q0 = pb * 4;

        // zero Oacc+Lsum slice (replaces hipMemsetAsync node): 513 float4/block
        for (int j = tid; j < 513; j += 256) zbase[pb * 513 + j] = float4{0.f, 0.f, 0.f, 0.f};

        const float4* asrc = (const float4*)(audio + q0 * 768);
        float4* adst = (float4*)a_lds;
        #pragma unroll
        for (int i = 0; i < 3; ++i) adst[i * 256 + tid] = asrc[i * 256 + tid];
        __syncthreads();

        float acc0[4] = {0.f, 0.f, 0.f, 0.f}, acc1[4] = {0.f, 0.f, 0.f, 0.f};
        #pragma unroll 4
        for (int d = 0; d < 768; ++d) {
            const float w0 = W[d * 512 + tid];
            const float w1 = W[d * 512 + 256 + tid];
            #pragma unroll
            for (int q = 0; q < 4; ++q) {
                const float a = a_lds[q * 768 + d];   // broadcast, conflict-free
                acc0[q] = fmaf(a, w0, acc0[q]);
                acc1[q] = fmaf(a, w1, acc1[q]);
            }
        }
        const float b0 = bias[tid], b1 = bias[256 + tid];
        #pragma unroll
        for (int q = 0; q < 4; ++q) {
            kw_lds[q * 512 + tid]       = acc0[q] + b0;
            kw_lds[q * 512 + 256 + tid] = acc1[q] + b1;
        }
        __syncthreads();

        const int w = tid >> 6;
        {   // wave w handles row w
            float ss = 0.f;
            #pragma unroll
            for (int i = 0; i < 8; ++i) { const float x = kw_lds[w * 512 + lane + i * 64]; ss = fmaf(x, x, ss); }
            #pragma unroll
            for (int o = 1; o < 64; o <<= 1) ss += __shfl_xor(ss, o);
            if (lane == 0) rn_lds[w] = 1.0f / fmaxf(sqrtf(ss), 1e-8f);
        }
        __syncthreads();
        #pragma unroll
        for (int i = 0; i < 8; ++i) {
            const int idx = i * 256 + tid;
            const int q = idx >> 9;
            kwn[(q0 + q) * 512 + (idx & 511)] = (bf16)(kw_lds[idx] * rn_lds[q]);
        }
    }
}

// ---------------- Kernel C: M64 producer/consumer fused attention ------------
// (unchanged from round 5: dist-2 3-buffer E streams both sides, producer-only
// setprio around S-MFMA cluster + exp/scatter, consumer early slot release.)
__global__ __launch_bounds__(768, 3) void k_attn(const bf16* __restrict__ kwn,
        const bf16* __restrict__ embS, const bf16* __restrict__ embT,
        const float* __restrict__ rs, float* __restrict__ Oacc,
        float* __restrict__ Lsum) {
    __shared__ unsigned short Qlds[64 * 512];       // 64 KB, XOR-swizzled granules
    __shared__ unsigned short Plds[2 * 16384];      // 64 KB: 2 slots x (64q x 256v)
    __shared__ int prod_done[2], cons_done[2];
    const int tid = threadIdx.x;
    const int s = blockIdx.x & (NSPLIT - 1), qt = blockIdx.x >> 4;
    const int q0 = qt * 64;
    const int wg = tid >> 6, lane = tid & 63, lm = lane & 15, lg = lane >> 4;

    if (tid < 2) { prod_done[tid] = 0; cons_done[tid] = 0; }
    if (tid < 512) {   // stage Q tile (64x512 bf16), granule-swizzled g' = g^(q&7)
        const uint4* src = (const uint4*)(kwn + q0 * 512);
        #pragma unroll
        for (int i = 0; i < 8; ++i) {
            const int L = (i * 512 + tid) * 8;
            const int q = L >> 9, g = (L & 511) >> 3;
            *(uint4*)&Qlds[q * 512 + ((g ^ (q & 7)) << 3)] = src[i * 512 + tid];
        }
    }
    __syncthreads();   // covers Q staging + flag init

    const f32x4 zero4 = {0.f, 0.f, 0.f, 0.f};
    const int c0 = (s * NCH) / NSPLIT, c1 = ((s + 1) * NCH) / NSPLIT;
    const int n = c1 - c0;

    if (wg < 4) {
        // ================= producer: v-slice wg*64, all 64 q =================
        float lacc[4][4];
        #pragma unroll
        for (int mb = 0; mb < 4; ++mb)
            #pragma unroll
            for (int r = 0; r < 4; ++r) lacc[mb][r] = 0.f;
        for (int i = 0; i < n; ++i) {
            const int c = c0 + i;
            const int slot = i & 1, use = i >> 1;
            // rs preload: off the post-wait critical path (flag-independent)
            float rsv4[4];
            #pragma unroll
            for (int nb = 0; nb < 4; ++nb)
                rsv4[nb] = rs[c * 256 + wg * 64 + nb * 16 + lm];
            // ---- S compute (flag-independent), distance-2 3-buffer E stream ----
            f32x4 sacc[4][4];
            #pragma unroll
            for (int mb = 0; mb < 4; ++mb)
                #pragma unroll
                for (int nb = 0; nb < 4; ++nb) sacc[mb][nb] = zero4;
            const bf16* Eb = embS + ((size_t)(c * 16 + wg * 4) * 16) * 512 + lane * 8;
            bf16x8 eb[3][4];
            #pragma unroll
            for (int nb = 0; nb < 4; ++nb) {
                eb[0][nb] = *(const bf16x8*)(Eb + (nb * 16) * 512);
                eb[1][nb] = *(const bf16x8*)(Eb + (nb * 16 + 1) * 512);
            }
            #pragma unroll
            for (int kf = 0; kf < 16; ++kf) {
                if (kf < 14) {     // distance-2 prefetch, static %3 rotation
                    #pragma unroll
                    for (int nb = 0; nb < 4; ++nb)
                        eb[(kf + 2) % 3][nb] = *(const bf16x8*)(Eb + (nb * 16 + kf + 2) * 512);
                }
                const int goff = ((kf * 4 + lg) ^ (lm & 7)) << 3;
                bf16x8 aq[4];
                #pragma unroll
                for (int mb = 0; mb < 4; ++mb)
                    aq[mb] = *(const bf16x8*)&Qlds[(mb * 16 + lm) * 512 + goff];
                __builtin_amdgcn_s_setprio(1);   // producer = P critical path
                #pragma unroll
                for (int nb = 0; nb < 4; ++nb)
                    #pragma unroll
                    for (int mb = 0; mb < 4; ++mb)
                        sacc[mb][nb] = __builtin_amdgcn_mfma_f32_16x16x32_bf16(aq[mb], eb[kf % 3][nb], sacc[mb][nb], 0, 0, 0);
                __builtin_amdgcn_s_setprio(0);
                __builtin_amdgcn_sched_barrier(0);
            }
            // ---- wait slot free (8 consumers), then exp + scatter ----
            while (__hip_atomic_load(&cons_done[slot], __ATOMIC_ACQUIRE,
                                     __HIP_MEMORY_SCOPE_WORKGROUP) < 8 * use)
                __builtin_amdgcn_s_sleep(1);
            unsigned short* Pw = Plds + (slot << 14);
            __builtin_amdgcn_s_setprio(1);       // scatter is also critical path
            #pragma unroll
            for (int nb = 0; nb < 4; ++nb) {
                const float rsv = rsv4[nb];
                const int kv = 2 * wg + (nb >> 1);
                const int lA = ((nb & 1) * 2 + (lm >> 3)) * 16;
                const int jj = lm & 7;
                #pragma unroll
                for (int mb = 0; mb < 4; ++mb) {
                    const int fragbase = (mb * 8 + kv) * 512;
                    #pragma unroll
                    for (int r = 0; r < 4; ++r) {
                        const float pv = __expf(sacc[mb][nb][r] * rsv);
                        const bf16 pb = (bf16)pv;
                        lacc[mb][r] += (float)pb;   // rounded value for consistency
                        const int ldest = lA + lg * 4 + r;
                        Pw[fragbase + ldest * 8 + jj] = __builtin_bit_cast(unsigned short, pb);
                    }
                }
            }
            __builtin_amdgcn_s_setprio(0);
            if (lane == 0)   // ONE increment per wave (release drains LDS writes)
                __hip_atomic_fetch_add(&prod_done[slot], 1, __ATOMIC_RELEASE,
                                       __HIP_MEMORY_SCOPE_WORKGROUP);
        }
        // Lsum: partial over this wave's v-slices, one atomic per q at the end
        #pragma unroll
        for (int mb = 0; mb < 4; ++mb)
            #pragma unroll
            for (int r = 0; r < 4; ++r) {
                float sum = lacc[mb][r];
                sum += __shfl_xor(sum, 1);
                sum += __shfl_xor(sum, 2);
                sum += __shfl_xor(sum, 4);
                sum += __shfl_xor(sum, 8);
                if (lm == 0) atomicAdd(&Lsum[q0 + mb * 16 + lg * 4 + r], sum);
            }
    } else {
        // ================= consumer: t-slice (wg-4)*64, all 64 q =============
        const int cw = wg - 4;
        f32x4 acc[4][4];                   // [mb 16q][nt 16t]
        #pragma unroll
        for (int mb = 0; mb < 4; ++mb)
            #pragma unroll
            for (int nt = 0; nt < 4; ++nt) acc[mb][nt] = zero4;
        for (int i = 0; i < n; ++i) {
            const int cc = c0 + i;
            const int slot = i & 1, use = i >> 1;
            const bf16* ETb = embT + ((size_t)cc * 256 + cw * 4) * 512 + lane * 8;
            // distance-2 3-buffer ET stream; kf=0,1 issued BEFORE the flag wait
            bf16x8 et[3][4];
            #pragma unroll
            for (int nt = 0; nt < 4; ++nt) {
                et[0][nt] = *(const bf16x8*)(ETb + nt * 512);
                et[1][nt] = *(const bf16x8*)(ETb + (32 + nt) * 512);
            }
            while (__hip_atomic_load(&prod_done[slot], __ATOMIC_ACQUIRE,
                                     __HIP_MEMORY_SCOPE_WORKGROUP) < 4 * (use + 1))
                __builtin_amdgcn_s_sleep(1);
            const unsigned short* Pb = Plds + (slot << 14);
            #pragma unroll
            for (int kf = 0; kf < 8; ++kf) {
                if (kf < 6) {      // distance-2 prefetch, static %3 rotation
                    #pragma unroll
                    for (int nt = 0; nt < 4; ++nt)
                        et[(kf + 2) % 3][nt] = *(const bf16x8*)(ETb + ((kf + 2) * 32 + nt) * 512);
                }
                bf16x8 pf[4];
                #pragma unroll
                for (int mb = 0; mb < 4; ++mb)
                    pf[mb] = *(const bf16x8*)&Pb[(mb * 8 + kf) * 512 + lane * 8];
                // early slot release: P regs loaded; trailing MFMAs are
                // register-only. RELEASE orders the LDS reads above.
                if (kf == 7 && lane == 0)
                    __hip_atomic_fetch_add(&cons_done[slot], 1, __ATOMIC_RELEASE,
                                           __HIP_MEMORY_SCOPE_WORKGROUP);
                #pragma unroll
                for (int nt = 0; nt < 4; ++nt)
                    #pragma unroll
                    for (int mb = 0; mb < 4; ++mb)
                        acc[mb][nt] = __builtin_amdgcn_mfma_f32_16x16x32_bf16(pf[mb], et[kf % 3][nt], acc[mb][nt], 0, 0, 0);
                __builtin_amdgcn_sched_barrier(0);
            }
        }
        // epilogue: combine partials across v-splits
        #pragma unroll
        for (int mb = 0; mb < 4; ++mb)
            #pragma unroll
            for (int nt = 0; nt < 4; ++nt)
                #pragma unroll
                for (int r = 0; r < 4; ++r) {
                    const int q = q0 + mb * 16 + lg * 4 + r;
                    const int t = cw * 64 + nt * 16 + lm;
                    atomicAdd(&Oacc[q * 512 + t], acc[mb][nt][r]);
                }
    }
}

// ---------------- Kernel D: out = Oacc / Lsum --------------------------------
__global__ __launch_bounds__(256) void k_final(const float* __restrict__ Oacc,
        const float* __restrict__ Lsum, float* __restrict__ out) {
    const int i = blockIdx.x * 256 + threadIdx.x;   // float4 index, 131072 total
    const float4 o = ((const float4*)Oacc)[i];
    const float inv = 1.0f / Lsum[i >> 7];          // 128 float4 per row
    float4 r;
    r.x = o.x * inv; r.y = o.y * inv; r.z = o.z * inv; r.w = o.w * inv;
    ((float4*)out)[i] = r;
}

// ---------------- launcher ---------------------------------------------------
// ws layout (bytes) — total 104,535,040 (proven to fit):
//   0        kwn   bf16 [1024*512]          1,048,576
//   1048576  rs    f32  [49408]               197,632
//   1246208  Oacc  f32  [1024*512]          2,097,152   (zeroed by k_pre proj blocks)
//   3343360  Lsum  f32  [1024]                   4,096   (zeroed by k_pre proj blocks)
//   3347456  embS  bf16 frag-major          50,593,792
//   53941248 embT  bf16 frag-major          50,593,792
extern "C" void kernel_launch(void* const* d_in, const int* in_sizes, int n_in,
                              void* d_out, int out_size, void* d_ws, size_t ws_size,
                              hipStream_t stream) {
    const float* audio = (const float*)d_in[0];
    const float* W     = (const float*)d_in[1];
    const float* bias  = (const float*)d_in[2];
    const float* emb   = (const float*)d_in[3];
    float* out = (float*)d_out;
    char* ws = (char*)d_ws;

    bf16*  kwn  = (bf16*)(ws);
    float* rs   = (float*)(ws + 1048576);
    float* Oacc = (float*)(ws + 1246208);
    float* Lsum = (float*)(ws + 3343360);
    bf16*  embS = (bf16*)(ws + 3347456);
    bf16*  embT = (bf16*)(ws + 53941248);
    float4* zbase = (float4*)(ws + 1246208);        // Oacc+Lsum contiguous, 131328 float4

    k_pre<<<NPROJ + NPREPB, 256, 0, stream>>>(emb, embS, embT, rs, audio, W, bias, kwn, zbase);
    k_attn<<<NQT * NSPLIT, 768, 0, stream>>>(kwn, embS, embT, rs, Oacc, Lsum);
    k_final<<<(out_size / 4) / 256, 256, 0, stream>>>(Oacc, Lsum, out);
}

// Round 9
// 332.550 us; speedup vs baseline: 1.3334x; 1.1400x over previous
//
#include <hip/hip_runtime.h>
#include <math.h>

// Problem constants: B=128,N=8 -> M=1024 rows; D=768; T=512; V=49408
#define VDIM    49408
#define NCH     193          // 49408 / 256 v-chunks
#define NSPLIT  16           // V splits; s = blockIdx&15 -> all 16 WGs of split on XCD s%8
#define NQT     16           // 1024 / 64 query tiles
#define NPROJ   256          // proj blocks FIRST (latency-bound, runs in prep's shadow)
#define NPREPB  1544         // VDIM/32 prep blocks (32-row tiles)

typedef __bf16 bf16;
typedef __bf16 bf16x8 __attribute__((ext_vector_type(8)));
typedef float  f32x4  __attribute__((ext_vector_type(4)));

// ---------------- Kernel AB (fused): proj (256 blocks) + prep (1544 blocks) --
// Round-9: (a) prep phase-1 remap: thread owns row tid>>3, cols (tid&7)+8j ->
// norm accumulates per-lane in REGISTERS (0 shuffles in the load loop; 3-step
// 8-lane reduce at the end). Kills the 96-DS-op/wave serial convoy that round-8
// counters (nothing saturated, 1.1TB/s) exposed. (b) proj W-loop: 16-deep
// register double-buffer (48 rounds of issue-32-loads || 128 FMAs) replaces
// unroll-4's 192 serial latency rounds under L2 thrash.
__global__ __launch_bounds__(256) void k_pre(const float* __restrict__ emb,
        bf16* __restrict__ embS, bf16* __restrict__ embT, float* __restrict__ rs,
        const float* __restrict__ audio, const float* __restrict__ W,
        const float* __restrict__ bias, bf16* __restrict__ kwn,
        float4* __restrict__ zbase) {
    __shared__ __align__(16) unsigned char smem[32 * 512 * 2 + 32 * 4];
    const int tid = threadIdx.x;
    const int lane = tid & 63;

    if (blockIdx.x >= NPROJ) {
        // ===================== prep branch: 32-row tile =====================
        unsigned short* tile = (unsigned short*)smem;          // 32x512 bf16
        float* pnorm = (float*)(smem + 32 * 512 * 2);          // 32 floats
        const int b = blockIdx.x - NPROJ;
        const int v0 = b * 32;

        // 1: row-per-thread-group loads (8 threads/row, 16 float4 each),
        //    per-lane register norm partials, bf16 convert + swizzled LDS store.
        const float4* src = (const float4*)(emb + (size_t)v0 * 512);
        const int row = tid >> 3;          // 0..31
        const int c8  = tid & 7;           // col group within row
        float ss0 = 0.f, ss1 = 0.f;
        #pragma unroll
        for (int ii = 0; ii < 2; ++ii) {
            float4 xb[8];
            #pragma unroll
            for (int j = 0; j < 8; ++j)
                xb[j] = src[row * 128 + c8 + (ii * 8 + j) * 8];
            #pragma unroll
            for (int j = 0; j < 8; ++j) {
                const float4 x = xb[j];
                if (j & 1) ss1 = fmaf(x.x, x.x, fmaf(x.y, x.y, fmaf(x.z, x.z, fmaf(x.w, x.w, ss1))));
                else       ss0 = fmaf(x.x, x.x, fmaf(x.y, x.y, fmaf(x.z, x.z, fmaf(x.w, x.w, ss0))));
                const int c4 = c8 + (ii * 8 + j) * 8;
                const int g = c4 >> 1, half = c4 & 1;
                ushort4 u;
                u.x = __builtin_bit_cast(unsigned short, (bf16)x.x);
                u.y = __builtin_bit_cast(unsigned short, (bf16)x.y);
                u.z = __builtin_bit_cast(unsigned short, (bf16)x.z);
                u.w = __builtin_bit_cast(unsigned short, (bf16)x.w);
                *(ushort4*)&tile[row * 512 + (((g ^ (row & 7)) << 3) + half * 4)] = u;
            }
        }
        {   // 8-lane reduce per row (rows are lane-aligned groups of 8)
            float ss = ss0 + ss1;
            ss += __shfl_xor(ss, 1);
            ss += __shfl_xor(ss, 2);
            ss += __shfl_xor(ss, 4);
            if (c8 == 0) pnorm[row] = ss;
        }
        __syncthreads();
        if (tid < 32)
            rs[v0 + tid] = 10.0f / fmaxf(sqrtf(pnorm[tid]), 1e-8f);   // folds 1/TEMP

        // 2: embS frag-major (uint4 LDS reads, coalesced global writes), 8 iters
        #pragma unroll
        for (int i = 0; i < 8; ++i) {
            const int F = i * 256 + tid;           // out granule 0..2047
            const int frag = F >> 6, l = F & 63;
            const int vt = frag >> 4, kf = frag & 15;   // vt 0..1
            const int lm = l & 15, lg = l >> 4;
            const int r = vt * 16 + lm, g = kf * 4 + lg;
            const uint4 d = *(const uint4*)&tile[r * 512 + ((g ^ (r & 7)) << 3)];
            *(uint4*)((unsigned short*)embS + ((size_t)(b * 2 + vt) * 16 + kf) * 512 + l * 8) = d;
        }
        // 3: embT frag-major (transpose gather from LDS, coalesced writes), 8 iters
        #pragma unroll
        for (int i = 0; i < 8; ++i) {
            const int F = i * 256 + tid;
            const int tt = F >> 6, l = F & 63;     // tt 0..31
            const int lm = l & 15, lg = l >> 4;
            const int t = tt * 16 + lm;
            unsigned short e[8];
            #pragma unroll
            for (int j = 0; j < 8; ++j) {
                const int r = lg * 8 + j;          // 0..31
                e[j] = tile[r * 512 + ((((t >> 3) ^ (r & 7)) << 3) + (t & 7))];
            }
            uint4 o;
            o.x = (unsigned)e[0] | ((unsigned)e[1] << 16);
            o.y = (unsigned)e[2] | ((unsigned)e[3] << 16);
            o.z = (unsigned)e[4] | ((unsigned)e[5] << 16);
            o.w = (unsigned)e[6] | ((unsigned)e[7] << 16);
            *(uint4*)((unsigned short*)embT + ((size_t)b * 32 + tt) * 512 + l * 8) = o;
        }
    } else {
        // ===================== proj branch (kw = audio@W + b, normalize) ====
        float* a_lds  = (float*)smem;                  // 4*768
        float* kw_lds = (float*)(smem + 12288);        // 4*512
        float* rn_lds = (float*)(smem + 20480);        // 4
        const int pb = blockIdx.x;
        const int q0 = pb * 4;

        // zero Oacc+Lsum slice (replaces hipMemsetAsync node): 513 float4/block
        for (int j = tid; j < 513; j += 256) zbase[pb * 513 + j] = float4{0.f, 0.f, 0.f, 0.f};

        const float4* asrc = (const float4*)(audio + q0 * 768);
        float4* adst = (float4*)a_lds;
        #pragma unroll
        for (int i = 0; i < 3; ++i) adst[i * 256 + tid] = asrc[i * 256 + tid];
        __syncthreads();

        // 16-deep register double-buffered W stream: 48 rounds, 32 loads in
        // flight while 128 FMAs execute -> latency covered, serial depth 48.
        float acc0[4] = {0.f, 0.f, 0.f, 0.f}, acc1[4] = {0.f, 0.f, 0.f, 0.f};
        float wa[16], wb[16];
        #pragma unroll
        for (int k = 0; k < 16; ++k) {
            wa[k] = W[k * 512 + tid];
            wb[k] = W[k * 512 + 256 + tid];
        }
        for (int dd = 0; dd < 48; ++dd) {
            float na[16], nb[16];
            if (dd < 47) {
                const int base = (dd + 1) * 16;
                #pragma unroll
                for (int k = 0; k < 16; ++k) {
                    na[k] = W[(base + k) * 512 + tid];
                    nb[k] = W[(base + k) * 512 + 256 + tid];
                }
            }
            #pragma unroll
            for (int k = 0; k < 16; ++k) {
                const int d = dd * 16 + k;
                #pragma unroll
                for (int q = 0; q < 4; ++q) {
                    const float a = a_lds[q * 768 + d];   // broadcast, conflict-free
                    acc0[q] = fmaf(a, wa[k], acc0[q]);
                    acc1[q] = fmaf(a, wb[k], acc1[q]);
                }
            }
            #pragma unroll
            for (int k = 0; k < 16; ++k) { wa[k] = na[k]; wb[k] = nb[k]; }
        }
        const float b0 = bias[tid], b1 = bias[256 + tid];
        #pragma unroll
        for (int q = 0; q < 4; ++q) {
            kw_lds[q * 512 + tid]       = acc0[q] + b0;
            kw_lds[q * 512 + 256 + tid] = acc1[q] + b1;
        }
        __syncthreads();

        const int w = tid >> 6;
        {   // wave w handles row w
            float ss = 0.f;
            #pragma unroll
            for (int i = 0; i < 8; ++i) { const float x = kw_lds[w * 512 + lane + i * 64]; ss = fmaf(x, x, ss); }
            #pragma unroll
            for (int o = 1; o < 64; o <<= 1) ss += __shfl_xor(ss, o);
            if (lane == 0) rn_lds[w] = 1.0f / fmaxf(sqrtf(ss), 1e-8f);
        }
        __syncthreads();
        #pragma unroll
        for (int i = 0; i < 8; ++i) {
            const int idx = i * 256 + tid;
            const int q = idx >> 9;
            kwn[(q0 + q) * 512 + (idx & 511)] = (bf16)(kw_lds[idx] * rn_lds[q]);
        }
    }
}

// ---------------- Kernel C: M64 producer/consumer fused attention ------------
// (unchanged from round 5/8: dist-2 3-buffer E streams both sides, producer-only
// setprio around S-MFMA cluster + exp/scatter, consumer early slot release.)
__global__ __launch_bounds__(768, 3) void k_attn(const bf16* __restrict__ kwn,
        const bf16* __restrict__ embS, const bf16* __restrict__ embT,
        const float* __restrict__ rs, float* __restrict__ Oacc,
        float* __restrict__ Lsum) {
    __shared__ unsigned short Qlds[64 * 512];       // 64 KB, XOR-swizzled granules
    __shared__ unsigned short Plds[2 * 16384];      // 64 KB: 2 slots x (64q x 256v)
    __shared__ int prod_done[2], cons_done[2];
    const int tid = threadIdx.x;
    const int s = blockIdx.x & (NSPLIT - 1), qt = blockIdx.x >> 4;
    const int q0 = qt * 64;
    const int wg = tid >> 6, lane = tid & 63, lm = lane & 15, lg = lane >> 4;

    if (tid < 2) { prod_done[tid] = 0; cons_done[tid] = 0; }
    if (tid < 512) {   // stage Q tile (64x512 bf16), granule-swizzled g' = g^(q&7)
        const uint4* src = (const uint4*)(kwn + q0 * 512);
        #pragma unroll
        for (int i = 0; i < 8; ++i) {
            const int L = (i * 512 + tid) * 8;
            const int q = L >> 9, g = (L & 511) >> 3;
            *(uint4*)&Qlds[q * 512 + ((g ^ (q & 7)) << 3)] = src[i * 512 + tid];
        }
    }
    __syncthreads();   // covers Q staging + flag init

    const f32x4 zero4 = {0.f, 0.f, 0.f, 0.f};
    const int c0 = (s * NCH) / NSPLIT, c1 = ((s + 1) * NCH) / NSPLIT;
    const int n = c1 - c0;

    if (wg < 4) {
        // ================= producer: v-slice wg*64, all 64 q =================
        float lacc[4][4];
        #pragma unroll
        for (int mb = 0; mb < 4; ++mb)
            #pragma unroll
            for (int r = 0; r < 4; ++r) lacc[mb][r] = 0.f;
        for (int i = 0; i < n; ++i) {
            const int c = c0 + i;
            const int slot = i & 1, use = i >> 1;
            // rs preload: off the post-wait critical path (flag-independent)
            float rsv4[4];
            #pragma unroll
            for (int nb = 0; nb < 4; ++nb)
                rsv4[nb] = rs[c * 256 + wg * 64 + nb * 16 + lm];
            // ---- S compute (flag-independent), distance-2 3-buffer E stream ----
            f32x4 sacc[4][4];
            #pragma unroll
            for (int mb = 0; mb < 4; ++mb)
                #pragma unroll
                for (int nb = 0; nb < 4; ++nb) sacc[mb][nb] = zero4;
            const bf16* Eb = embS + ((size_t)(c * 16 + wg * 4) * 16) * 512 + lane * 8;
            bf16x8 eb[3][4];
            #pragma unroll
            for (int nb = 0; nb < 4; ++nb) {
                eb[0][nb] = *(const bf16x8*)(Eb + (nb * 16) * 512);
                eb[1][nb] = *(const bf16x8*)(Eb + (nb * 16 + 1) * 512);
            }
            #pragma unroll
            for (int kf = 0; kf < 16; ++kf) {
                if (kf < 14) {     // distance-2 prefetch, static %3 rotation
                    #pragma unroll
                    for (int nb = 0; nb < 4; ++nb)
                        eb[(kf + 2) % 3][nb] = *(const bf16x8*)(Eb + (nb * 16 + kf + 2) * 512);
                }
                const int goff = ((kf * 4 + lg) ^ (lm & 7)) << 3;
                bf16x8 aq[4];
                #pragma unroll
                for (int mb = 0; mb < 4; ++mb)
                    aq[mb] = *(const bf16x8*)&Qlds[(mb * 16 + lm) * 512 + goff];
                __builtin_amdgcn_s_setprio(1);   // producer = P critical path
                #pragma unroll
                for (int nb = 0; nb < 4; ++nb)
                    #pragma unroll
                    for (int mb = 0; mb < 4; ++mb)
                        sacc[mb][nb] = __builtin_amdgcn_mfma_f32_16x16x32_bf16(aq[mb], eb[kf % 3][nb], sacc[mb][nb], 0, 0, 0);
                __builtin_amdgcn_s_setprio(0);
                __builtin_amdgcn_sched_barrier(0);
            }
            // ---- wait slot free (8 consumers), then exp + scatter ----
            while (__hip_atomic_load(&cons_done[slot], __ATOMIC_ACQUIRE,
                                     __HIP_MEMORY_SCOPE_WORKGROUP) < 8 * use)
                __builtin_amdgcn_s_sleep(1);
            unsigned short* Pw = Plds + (slot << 14);
            __builtin_amdgcn_s_setprio(1);       // scatter is also critical path
            #pragma unroll
            for (int nb = 0; nb < 4; ++nb) {
                const float rsv = rsv4[nb];
                const int kv = 2 * wg + (nb >> 1);
                const int lA = ((nb & 1) * 2 + (lm >> 3)) * 16;
                const int jj = lm & 7;
                #pragma unroll
                for (int mb = 0; mb < 4; ++mb) {
                    const int fragbase = (mb * 8 + kv) * 512;
                    #pragma unroll
                    for (int r = 0; r < 4; ++r) {
                        const float pv = __expf(sacc[mb][nb][r] * rsv);
                        const bf16 pb = (bf16)pv;
                        lacc[mb][r] += (float)pb;   // rounded value for consistency
                        const int ldest = lA + lg * 4 + r;
                        Pw[fragbase + ldest * 8 + jj] = __builtin_bit_cast(unsigned short, pb);
                    }
                }
            }
            __builtin_amdgcn_s_setprio(0);
            if (lane == 0)   // ONE increment per wave (release drains LDS writes)
                __hip_atomic_fetch_add(&prod_done[slot], 1, __ATOMIC_RELEASE,
                                       __HIP_MEMORY_SCOPE_WORKGROUP);
        }
        // Lsum: partial over this wave's v-slices, one atomic per q at the end
        #pragma unroll
        for (int mb = 0; mb < 4; ++mb)
            #pragma unroll
            for (int r = 0; r < 4; ++r) {
                float sum = lacc[mb][r];
                sum += __shfl_xor(sum, 1);
                sum += __shfl_xor(sum, 2);
                sum += __shfl_xor(sum, 4);
                sum += __shfl_xor(sum, 8);
                if (lm == 0) atomicAdd(&Lsum[q0 + mb * 16 + lg * 4 + r], sum);
            }
    } else {
        // ================= consumer: t-slice (wg-4)*64, all 64 q =============
        const int cw = wg - 4;
        f32x4 acc[4][4];                   // [mb 16q][nt 16t]
        #pragma unroll
        for (int mb = 0; mb < 4; ++mb)
            #pragma unroll
            for (int nt = 0; nt < 4; ++nt) acc[mb][nt] = zero4;
        for (int i = 0; i < n; ++i) {
            const int cc = c0 + i;
            const int slot = i & 1, use = i >> 1;
            const bf16* ETb = embT + ((size_t)cc * 256 + cw * 4) * 512 + lane * 8;
            // distance-2 3-buffer ET stream; kf=0,1 issued BEFORE the flag wait
            bf16x8 et[3][4];
            #pragma unroll
            for (int nt = 0; nt < 4; ++nt) {
                et[0][nt] = *(const bf16x8*)(ETb + nt * 512);
                et[1][nt] = *(const bf16x8*)(ETb + (32 + nt) * 512);
            }
            while (__hip_atomic_load(&prod_done[slot], __ATOMIC_ACQUIRE,
                                     __HIP_MEMORY_SCOPE_WORKGROUP) < 4 * (use + 1))
                __builtin_amdgcn_s_sleep(1);
            const unsigned short* Pb = Plds + (slot << 14);
            #pragma unroll
            for (int kf = 0; kf < 8; ++kf) {
                if (kf < 6) {      // distance-2 prefetch, static %3 rotation
                    #pragma unroll
                    for (int nt = 0; nt < 4; ++nt)
                        et[(kf + 2) % 3][nt] = *(const bf16x8*)(ETb + ((kf + 2) * 32 + nt) * 512);
                }
                bf16x8 pf[4];
                #pragma unroll
                for (int mb = 0; mb < 4; ++mb)
                    pf[mb] = *(const bf16x8*)&Pb[(mb * 8 + kf) * 512 + lane * 8];
                // early slot release: P regs loaded; trailing MFMAs are
                // register-only. RELEASE orders the LDS reads above.
                if (kf == 7 && lane == 0)
                    __hip_atomic_fetch_add(&cons_done[slot], 1, __ATOMIC_RELEASE,
                                           __HIP_MEMORY_SCOPE_WORKGROUP);
                #pragma unroll
                for (int nt = 0; nt < 4; ++nt)
                    #pragma unroll
                    for (int mb = 0; mb < 4; ++mb)
                        acc[mb][nt] = __builtin_amdgcn_mfma_f32_16x16x32_bf16(pf[mb], et[kf % 3][nt], acc[mb][nt], 0, 0, 0);
                __builtin_amdgcn_sched_barrier(0);
            }
        }
        // epilogue: combine partials across v-splits
        #pragma unroll
        for (int mb = 0; mb < 4; ++mb)
            #pragma unroll
            for (int nt = 0; nt < 4; ++nt)
                #pragma unroll
                for (int r = 0; r < 4; ++r) {
                    const int q = q0 + mb * 16 + lg * 4 + r;
                    const int t = cw * 64 + nt * 16 + lm;
                    atomicAdd(&Oacc[q * 512 + t], acc[mb][nt][r]);
                }
    }
}

// ---------------- Kernel D: out = Oacc / Lsum --------------------------------
__global__ __launch_bounds__(256) void k_final(const float* __restrict__ Oacc,
        const float* __restrict__ Lsum, float* __restrict__ out) {
    const int i = blockIdx.x * 256 + threadIdx.x;   // float4 index, 131072 total
    const float4 o = ((const float4*)Oacc)[i];
    const float inv = 1.0f / Lsum[i >> 7];          // 128 float4 per row
    float4 r;
    r.x = o.x * inv; r.y = o.y * inv; r.z = o.z * inv; r.w = o.w * inv;
    ((float4*)out)[i] = r;
}

// ---------------- launcher ---------------------------------------------------
// ws layout (bytes) — total 104,535,040 (proven to fit):
//   0        kwn   bf16 [1024*512]          1,048,576
//   1048576  rs    f32  [49408]               197,632
//   1246208  Oacc  f32  [1024*512]          2,097,152   (zeroed by k_pre proj blocks)
//   3343360  Lsum  f32  [1024]                   4,096   (zeroed by k_pre proj blocks)
//   3347456  embS  bf16 frag-major          50,593,792
//   53941248 embT  bf16 frag-major          50,593,792
extern "C" void kernel_launch(void* const* d_in, const int* in_sizes, int n_in,
                              void* d_out, int out_size, void* d_ws, size_t ws_size,
                              hipStream_t stream) {
    const float* audio = (const float*)d_in[0];
    const float* W     = (const float*)d_in[1];
    const float* bias  = (const float*)d_in[2];
    const float* emb   = (const float*)d_in[3];
    float* out = (float*)d_out;
    char* ws = (char*)d_ws;

    bf16*  kwn  = (bf16*)(ws);
    float* rs   = (float*)(ws + 1048576);
    float* Oacc = (float*)(ws + 1246208);
    float* Lsum = (float*)(ws + 3343360);
    bf16*  embS = (bf16*)(ws + 3347456);
    bf16*  embT = (bf16*)(ws + 53941248);
    float4* zbase = (float4*)(ws + 1246208);        // Oacc+Lsum contiguous, 131328 float4

    k_pre<<<NPROJ + NPREPB, 256, 0, stream>>>(emb, embS, embT, rs, audio, W, bias, kwn, zbase);
    k_attn<<<NQT * NSPLIT, 768, 0, stream>>>(kwn, embS, embT, rs, Oacc, Lsum);
    k_final<<<(out_size / 4) / 256, 256, 0, stream>>>(Oacc, Lsum, out);
}

// Round 10
// 310.072 us; speedup vs baseline: 1.4301x; 1.0725x over previous
//
#include <hip/hip_runtime.h>
#include <math.h>

// Problem constants: B=128,N=8 -> M=1024 rows; D=768; T=512; V=49408
#define VDIM    49408
#define NCH     193          // 49408 / 256 v-chunks
#define NSPLIT  16           // V splits; s = blockIdx&15 -> all 16 WGs of split on XCD s%8
#define NQT     16           // 1024 / 64 query tiles
#define NPROJ   256          // proj blocks FIRST (latency-bound, runs in prep's shadow)
#define NPREPB  1544         // VDIM/32 prep blocks (32-row tiles)

typedef __bf16 bf16;
typedef __bf16 bf16x8 __attribute__((ext_vector_type(8)));
typedef float  f32x4  __attribute__((ext_vector_type(4)));

// ---------------- Kernel AB (fused): proj (256 blocks) + prep (1544 blocks) --
// (round-9 version, kept: row-per-thread-group register norm, 16-deep W dbuf)
__global__ __launch_bounds__(256) void k_pre(const float* __restrict__ emb,
        bf16* __restrict__ embS, bf16* __restrict__ embT, float* __restrict__ rs,
        const float* __restrict__ audio, const float* __restrict__ W,
        const float* __restrict__ bias, bf16* __restrict__ kwn,
        float4* __restrict__ zbase) {
    __shared__ __align__(16) unsigned char smem[32 * 512 * 2 + 32 * 4];
    const int tid = threadIdx.x;
    const int lane = tid & 63;

    if (blockIdx.x >= NPROJ) {
        // ===================== prep branch: 32-row tile =====================
        unsigned short* tile = (unsigned short*)smem;          // 32x512 bf16
        float* pnorm = (float*)(smem + 32 * 512 * 2);          // 32 floats
        const int b = blockIdx.x - NPROJ;
        const int v0 = b * 32;

        // 1: row-per-thread-group loads (8 threads/row, 16 float4 each),
        //    per-lane register norm partials, bf16 convert + swizzled LDS store.
        const float4* src = (const float4*)(emb + (size_t)v0 * 512);
        const int row = tid >> 3;          // 0..31
        const int c8  = tid & 7;           // col group within row
        float ss0 = 0.f, ss1 = 0.f;
        #pragma unroll
        for (int ii = 0; ii < 2; ++ii) {
            float4 xb[8];
            #pragma unroll
            for (int j = 0; j < 8; ++j)
                xb[j] = src[row * 128 + c8 + (ii * 8 + j) * 8];
            #pragma unroll
            for (int j = 0; j < 8; ++j) {
                const float4 x = xb[j];
                if (j & 1) ss1 = fmaf(x.x, x.x, fmaf(x.y, x.y, fmaf(x.z, x.z, fmaf(x.w, x.w, ss1))));
                else       ss0 = fmaf(x.x, x.x, fmaf(x.y, x.y, fmaf(x.z, x.z, fmaf(x.w, x.w, ss0))));
                const int c4 = c8 + (ii * 8 + j) * 8;
                const int g = c4 >> 1, half = c4 & 1;
                ushort4 u;
                u.x = __builtin_bit_cast(unsigned short, (bf16)x.x);
                u.y = __builtin_bit_cast(unsigned short, (bf16)x.y);
                u.z = __builtin_bit_cast(unsigned short, (bf16)x.z);
                u.w = __builtin_bit_cast(unsigned short, (bf16)x.w);
                *(ushort4*)&tile[row * 512 + (((g ^ (row & 7)) << 3) + half * 4)] = u;
            }
        }
        {   // 8-lane reduce per row (rows are lane-aligned groups of 8)
            float ss = ss0 + ss1;
            ss += __shfl_xor(ss, 1);
            ss += __shfl_xor(ss, 2);
            ss += __shfl_xor(ss, 4);
            if (c8 == 0) pnorm[row] = ss;
        }
        __syncthreads();
        if (tid < 32)
            rs[v0 + tid] = 10.0f / fmaxf(sqrtf(pnorm[tid]), 1e-8f);   // folds 1/TEMP

        // 2: embS frag-major (uint4 LDS reads, coalesced global writes), 8 iters
        #pragma unroll
        for (int i = 0; i < 8; ++i) {
            const int F = i * 256 + tid;           // out granule 0..2047
            const int frag = F >> 6, l = F & 63;
            const int vt = frag >> 4, kf = frag & 15;   // vt 0..1
            const int lm = l & 15, lg = l >> 4;
            const int r = vt * 16 + lm, g = kf * 4 + lg;
            const uint4 d = *(const uint4*)&tile[r * 512 + ((g ^ (r & 7)) << 3)];
            *(uint4*)((unsigned short*)embS + ((size_t)(b * 2 + vt) * 16 + kf) * 512 + l * 8) = d;
        }
        // 3: embT frag-major (transpose gather from LDS, coalesced writes), 8 iters
        #pragma unroll
        for (int i = 0; i < 8; ++i) {
            const int F = i * 256 + tid;
            const int tt = F >> 6, l = F & 63;     // tt 0..31
            const int lm = l & 15, lg = l >> 4;
            const int t = tt * 16 + lm;
            unsigned short e[8];
            #pragma unroll
            for (int j = 0; j < 8; ++j) {
                const int r = lg * 8 + j;          // 0..31
                e[j] = tile[r * 512 + ((((t >> 3) ^ (r & 7)) << 3) + (t & 7))];
            }
            uint4 o;
            o.x = (unsigned)e[0] | ((unsigned)e[1] << 16);
            o.y = (unsigned)e[2] | ((unsigned)e[3] << 16);
            o.z = (unsigned)e[4] | ((unsigned)e[5] << 16);
            o.w = (unsigned)e[6] | ((unsigned)e[7] << 16);
            *(uint4*)((unsigned short*)embT + ((size_t)b * 32 + tt) * 512 + l * 8) = o;
        }
    } else {
        // ===================== proj branch (kw = audio@W + b, normalize) ====
        float* a_lds  = (float*)smem;                  // 4*768
        float* kw_lds = (float*)(smem + 12288);        // 4*512
        float* rn_lds = (float*)(smem + 20480);        // 4
        const int pb = blockIdx.x;
        const int q0 = pb * 4;

        // zero Oacc+Lsum slice (replaces hipMemsetAsync node): 513 float4/block
        for (int j = tid; j < 513; j += 256) zbase[pb * 513 + j] = float4{0.f, 0.f, 0.f, 0.f};

        const float4* asrc = (const float4*)(audio + q0 * 768);
        float4* adst = (float4*)a_lds;
        #pragma unroll
        for (int i = 0; i < 3; ++i) adst[i * 256 + tid] = asrc[i * 256 + tid];
        __syncthreads();

        // 16-deep register double-buffered W stream: 48 rounds, 32 loads in
        // flight while 128 FMAs execute -> latency covered, serial depth 48.
        float acc0[4] = {0.f, 0.f, 0.f, 0.f}, acc1[4] = {0.f, 0.f, 0.f, 0.f};
        float wa[16], wb[16];
        #pragma unroll
        for (int k = 0; k < 16; ++k) {
            wa[k] = W[k * 512 + tid];
            wb[k] = W[k * 512 + 256 + tid];
        }
        for (int dd = 0; dd < 48; ++dd) {
            float na[16], nb[16];
            if (dd < 47) {
                const int base = (dd + 1) * 16;
                #pragma unroll
                for (int k = 0; k < 16; ++k) {
                    na[k] = W[(base + k) * 512 + tid];
                    nb[k] = W[(base + k) * 512 + 256 + tid];
                }
            }
            #pragma unroll
            for (int k = 0; k < 16; ++k) {
                const int d = dd * 16 + k;
                #pragma unroll
                for (int q = 0; q < 4; ++q) {
                    const float a = a_lds[q * 768 + d];   // broadcast, conflict-free
                    acc0[q] = fmaf(a, wa[k], acc0[q]);
                    acc1[q] = fmaf(a, wb[k], acc1[q]);
                }
            }
            #pragma unroll
            for (int k = 0; k < 16; ++k) { wa[k] = na[k]; wb[k] = nb[k]; }
        }
        const float b0 = bias[tid], b1 = bias[256 + tid];
        #pragma unroll
        for (int q = 0; q < 4; ++q) {
            kw_lds[q * 512 + tid]       = acc0[q] + b0;
            kw_lds[q * 512 + 256 + tid] = acc1[q] + b1;
        }
        __syncthreads();

        const int w = tid >> 6;
        {   // wave w handles row w
            float ss = 0.f;
            #pragma unroll
            for (int i = 0; i < 8; ++i) { const float x = kw_lds[w * 512 + lane + i * 64]; ss = fmaf(x, x, ss); }
            #pragma unroll
            for (int o = 1; o < 64; o <<= 1) ss += __shfl_xor(ss, o);
            if (lane == 0) rn_lds[w] = 1.0f / fmaxf(sqrtf(ss), 1e-8f);
        }
        __syncthreads();
        #pragma unroll
        for (int i = 0; i < 8; ++i) {
            const int idx = i * 256 + tid;
            const int q = idx >> 9;
            kwn[(q0 + q) * 512 + (idx & 511)] = (bf16)(kw_lds[idx] * rn_lds[q]);
        }
    }
}

// ---------------- Kernel C: M64 producer/consumer fused attention ------------
// REVERTED to the round-4 117us version: dist-2 3-buffer E streams + rs hoist,
// NO setprio, NO early slot release. Round-9 profile exposed that the round-5
// "trims" (shipped unmeasured, masked by k_pre in top-5) cost 117->137us /
// MfmaUtil 38.7->32%: producer setprio starved the 2x-FLOPs consumer waves on
// shared SIMDs, and lane-0-release-before-last-MFMA doesn't order other lanes'
// in-flight LDS reads (latent race).
__global__ __launch_bounds__(768, 3) void k_attn(const bf16* __restrict__ kwn,
        const bf16* __restrict__ embS, const bf16* __restrict__ embT,
        const float* __restrict__ rs, float* __restrict__ Oacc,
        float* __restrict__ Lsum) {
    __shared__ unsigned short Qlds[64 * 512];       // 64 KB, XOR-swizzled granules
    __shared__ unsigned short Plds[2 * 16384];      // 64 KB: 2 slots x (64q x 256v)
    __shared__ int prod_done[2], cons_done[2];
    const int tid = threadIdx.x;
    const int s = blockIdx.x & (NSPLIT - 1), qt = blockIdx.x >> 4;
    const int q0 = qt * 64;
    const int wg = tid >> 6, lane = tid & 63, lm = lane & 15, lg = lane >> 4;

    if (tid < 2) { prod_done[tid] = 0; cons_done[tid] = 0; }
    if (tid < 512) {   // stage Q tile (64x512 bf16), granule-swizzled g' = g^(q&7)
        const uint4* src = (const uint4*)(kwn + q0 * 512);
        #pragma unroll
        for (int i = 0; i < 8; ++i) {
            const int L = (i * 512 + tid) * 8;
            const int q = L >> 9, g = (L & 511) >> 3;
            *(uint4*)&Qlds[q * 512 + ((g ^ (q & 7)) << 3)] = src[i * 512 + tid];
        }
    }
    __syncthreads();   // covers Q staging + flag init

    const f32x4 zero4 = {0.f, 0.f, 0.f, 0.f};
    const int c0 = (s * NCH) / NSPLIT, c1 = ((s + 1) * NCH) / NSPLIT;
    const int n = c1 - c0;

    if (wg < 4) {
        // ================= producer: v-slice wg*64, all 64 q =================
        float lacc[4][4];
        #pragma unroll
        for (int mb = 0; mb < 4; ++mb)
            #pragma unroll
            for (int r = 0; r < 4; ++r) lacc[mb][r] = 0.f;
        for (int i = 0; i < n; ++i) {
            const int c = c0 + i;
            const int slot = i & 1, use = i >> 1;
            // rs preload: off the post-wait critical path (flag-independent)
            float rsv4[4];
            #pragma unroll
            for (int nb = 0; nb < 4; ++nb)
                rsv4[nb] = rs[c * 256 + wg * 64 + nb * 16 + lm];
            // ---- S compute (flag-independent), distance-2 3-buffer E stream ----
            f32x4 sacc[4][4];
            #pragma unroll
            for (int mb = 0; mb < 4; ++mb)
                #pragma unroll
                for (int nb = 0; nb < 4; ++nb) sacc[mb][nb] = zero4;
            const bf16* Eb = embS + ((size_t)(c * 16 + wg * 4) * 16) * 512 + lane * 8;
            bf16x8 eb[3][4];
            #pragma unroll
            for (int nb = 0; nb < 4; ++nb) {
                eb[0][nb] = *(const bf16x8*)(Eb + (nb * 16) * 512);
                eb[1][nb] = *(const bf16x8*)(Eb + (nb * 16 + 1) * 512);
            }
            #pragma unroll
            for (int kf = 0; kf < 16; ++kf) {
                if (kf < 14) {     // distance-2 prefetch, static %3 rotation
                    #pragma unroll
                    for (int nb = 0; nb < 4; ++nb)
                        eb[(kf + 2) % 3][nb] = *(const bf16x8*)(Eb + (nb * 16 + kf + 2) * 512);
                }
                const int goff = ((kf * 4 + lg) ^ (lm & 7)) << 3;
                bf16x8 aq[4];
                #pragma unroll
                for (int mb = 0; mb < 4; ++mb)
                    aq[mb] = *(const bf16x8*)&Qlds[(mb * 16 + lm) * 512 + goff];
                #pragma unroll
                for (int nb = 0; nb < 4; ++nb)
                    #pragma unroll
                    for (int mb = 0; mb < 4; ++mb)
                        sacc[mb][nb] = __builtin_amdgcn_mfma_f32_16x16x32_bf16(aq[mb], eb[kf % 3][nb], sacc[mb][nb], 0, 0, 0);
                __builtin_amdgcn_sched_barrier(0);
            }
            // ---- wait slot free (8 consumers), then exp + scatter ----
            while (__hip_atomic_load(&cons_done[slot], __ATOMIC_ACQUIRE,
                                     __HIP_MEMORY_SCOPE_WORKGROUP) < 8 * use)
                __builtin_amdgcn_s_sleep(1);
            unsigned short* Pw = Plds + (slot << 14);
            #pragma unroll
            for (int nb = 0; nb < 4; ++nb) {
                const float rsv = rsv4[nb];
                const int kv = 2 * wg + (nb >> 1);
                const int lA = ((nb & 1) * 2 + (lm >> 3)) * 16;
                const int jj = lm & 7;
                #pragma unroll
                for (int mb = 0; mb < 4; ++mb) {
                    const int fragbase = (mb * 8 + kv) * 512;
                    #pragma unroll
                    for (int r = 0; r < 4; ++r) {
                        const float pv = __expf(sacc[mb][nb][r] * rsv);
                        const bf16 pb = (bf16)pv;
                        lacc[mb][r] += (float)pb;   // rounded value for consistency
                        const int ldest = lA + lg * 4 + r;
                        Pw[fragbase + ldest * 8 + jj] = __builtin_bit_cast(unsigned short, pb);
                    }
                }
            }
            if (lane == 0)   // ONE increment per wave (release drains LDS writes)
                __hip_atomic_fetch_add(&prod_done[slot], 1, __ATOMIC_RELEASE,
                                       __HIP_MEMORY_SCOPE_WORKGROUP);
        }
        // Lsum: partial over this wave's v-slices, one atomic per q at the end
        #pragma unroll
        for (int mb = 0; mb < 4; ++mb)
            #pragma unroll
            for (int r = 0; r < 4; ++r) {
                float sum = lacc[mb][r];
                sum += __shfl_xor(sum, 1);
                sum += __shfl_xor(sum, 2);
                sum += __shfl_xor(sum, 4);
                sum += __shfl_xor(sum, 8);
                if (lm == 0) atomicAdd(&Lsum[q0 + mb * 16 + lg * 4 + r], sum);
            }
    } else {
        // ================= consumer: t-slice (wg-4)*64, all 64 q =============
        const int cw = wg - 4;
        f32x4 acc[4][4];                   // [mb 16q][nt 16t]
        #pragma unroll
        for (int mb = 0; mb < 4; ++mb)
            #pragma unroll
            for (int nt = 0; nt < 4; ++nt) acc[mb][nt] = zero4;
        for (int i = 0; i < n; ++i) {
            const int cc = c0 + i;
            const int slot = i & 1, use = i >> 1;
            const bf16* ETb = embT + ((size_t)cc * 256 + cw * 4) * 512 + lane * 8;
            // distance-2 3-buffer ET stream; kf=0,1 issued BEFORE the flag wait
            bf16x8 et[3][4];
            #pragma unroll
            for (int nt = 0; nt < 4; ++nt) {
                et[0][nt] = *(const bf16x8*)(ETb + nt * 512);
                et[1][nt] = *(const bf16x8*)(ETb + (32 + nt) * 512);
            }
            while (__hip_atomic_load(&prod_done[slot], __ATOMIC_ACQUIRE,
                                     __HIP_MEMORY_SCOPE_WORKGROUP) < 4 * (use + 1))
                __builtin_amdgcn_s_sleep(1);
            const unsigned short* Pb = Plds + (slot << 14);
            #pragma unroll
            for (int kf = 0; kf < 8; ++kf) {
                if (kf < 6) {      // distance-2 prefetch, static %3 rotation
                    #pragma unroll
                    for (int nt = 0; nt < 4; ++nt)
                        et[(kf + 2) % 3][nt] = *(const bf16x8*)(ETb + ((kf + 2) * 32 + nt) * 512);
                }
                bf16x8 pf[4];
                #pragma unroll
                for (int mb = 0; mb < 4; ++mb)
                    pf[mb] = *(const bf16x8*)&Pb[(mb * 8 + kf) * 512 + lane * 8];
                #pragma unroll
                for (int nt = 0; nt < 4; ++nt)
                    #pragma unroll
                    for (int mb = 0; mb < 4; ++mb)
                        acc[mb][nt] = __builtin_amdgcn_mfma_f32_16x16x32_bf16(pf[mb], et[kf % 3][nt], acc[mb][nt], 0, 0, 0);
                __builtin_amdgcn_sched_barrier(0);
            }
            if (lane == 0)   // ONE increment per wave (release drains LDS reads)
                __hip_atomic_fetch_add(&cons_done[slot], 1, __ATOMIC_RELEASE,
                                       __HIP_MEMORY_SCOPE_WORKGROUP);
        }
        // epilogue: combine partials across v-splits
        #pragma unroll
        for (int mb = 0; mb < 4; ++mb)
            #pragma unroll
            for (int nt = 0; nt < 4; ++nt)
                #pragma unroll
                for (int r = 0; r < 4; ++r) {
                    const int q = q0 + mb * 16 + lg * 4 + r;
                    const int t = cw * 64 + nt * 16 + lm;
                    atomicAdd(&Oacc[q * 512 + t], acc[mb][nt][r]);
                }
    }
}

// ---------------- Kernel D: out = Oacc / Lsum --------------------------------
__global__ __launch_bounds__(256) void k_final(const float* __restrict__ Oacc,
        const float* __restrict__ Lsum, float* __restrict__ out) {
    const int i = blockIdx.x * 256 + threadIdx.x;   // float4 index, 131072 total
    const float4 o = ((const float4*)Oacc)[i];
    const float inv = 1.0f / Lsum[i >> 7];          // 128 float4 per row
    float4 r;
    r.x = o.x * inv; r.y = o.y * inv; r.z = o.z * inv; r.w = o.w * inv;
    ((float4*)out)[i] = r;
}

// ---------------- launcher ---------------------------------------------------
// ws layout (bytes) — total 104,535,040 (proven to fit):
//   0        kwn   bf16 [1024*512]          1,048,576
//   1048576  rs    f32  [49408]               197,632
//   1246208  Oacc  f32  [1024*512]          2,097,152   (zeroed by k_pre proj blocks)
//   3343360  Lsum  f32  [1024]                   4,096   (zeroed by k_pre proj blocks)
//   3347456  embS  bf16 frag-major          50,593,792
//   53941248 embT  bf16 frag-major          50,593,792
extern "C" void kernel_launch(void* const* d_in, const int* in_sizes, int n_in,
                              void* d_out, int out_size, void* d_ws, size_t ws_size,
                              hipStream_t stream) {
    const float* audio = (const float*)d_in[0];
    const float* W     = (const float*)d_in[1];
    const float* bias  = (const float*)d_in[2];
    const float* emb   = (const float*)d_in[3];
    float* out = (float*)d_out;
    char* ws = (char*)d_ws;

    bf16*  kwn  = (bf16*)(ws);
    float* rs   = (float*)(ws + 1048576);
    float* Oacc = (float*)(ws + 1246208);
    float* Lsum = (float*)(ws + 3343360);
    bf16*  embS = (bf16*)(ws + 3347456);
    bf16*  embT = (bf16*)(ws + 53941248);
    float4* zbase = (float4*)(ws + 1246208);        // Oacc+Lsum contiguous, 131328 float4

    k_pre<<<NPROJ + NPREPB, 256, 0, stream>>>(emb, embS, embT, rs, audio, W, bias, kwn, zbase);
    k_attn<<<NQT * NSPLIT, 768, 0, stream>>>(kwn, embS, embT, rs, Oacc, Lsum);
    k_final<<<(out_size / 4) / 256, 256, 0, stream>>>(Oacc, Lsum, out);
}

// Round 12
// 306.498 us; speedup vs baseline: 1.4467x; 1.0117x over previous
//
#include <hip/hip_runtime.h>
#include <math.h>

// Problem constants: B=128,N=8 -> M=1024 rows; D=768; T=512; V=49408
#define VDIM    49408
#define NCH     193          // 49408 / 256 v-chunks
#define NSPLIT  16           // V splits; s = blockIdx&15 -> all 16 WGs of split on XCD s%8
#define NQT     16           // 1024 / 64 query tiles
#define NPROJ   256          // proj blocks FIRST (latency-bound, runs in prep's shadow)
#define NPREPB  1544         // VDIM/32 prep blocks (32-row tiles)

typedef __bf16 bf16;
typedef __bf16 bf16x8 __attribute__((ext_vector_type(8)));
typedef float  f32x4  __attribute__((ext_vector_type(4)));

// ---------------- Kernel AB (fused): proj (256 blocks) + prep (1544 blocks) --
// (round-9/10 version, frozen: row-per-thread-group register norm, 16-deep W dbuf)
__global__ __launch_bounds__(256) void k_pre(const float* __restrict__ emb,
        bf16* __restrict__ embS, bf16* __restrict__ embT, float* __restrict__ rs,
        const float* __restrict__ audio, const float* __restrict__ W,
        const float* __restrict__ bias, bf16* __restrict__ kwn,
        float4* __restrict__ zbase) {
    __shared__ __align__(16) unsigned char smem[32 * 512 * 2 + 32 * 4];
    const int tid = threadIdx.x;
    const int lane = tid & 63;

    if (blockIdx.x >= NPROJ) {
        // ===================== prep branch: 32-row tile =====================
        unsigned short* tile = (unsigned short*)smem;          // 32x512 bf16
        float* pnorm = (float*)(smem + 32 * 512 * 2);          // 32 floats
        const int b = blockIdx.x - NPROJ;
        const int v0 = b * 32;

        // 1: row-per-thread-group loads (8 threads/row, 16 float4 each),
        //    per-lane register norm partials, bf16 convert + swizzled LDS store.
        const float4* src = (const float4*)(emb + (size_t)v0 * 512);
        const int row = tid >> 3;          // 0..31
        const int c8  = tid & 7;           // col group within row
        float ss0 = 0.f, ss1 = 0.f;
        #pragma unroll
        for (int ii = 0; ii < 2; ++ii) {
            float4 xb[8];
            #pragma unroll
            for (int j = 0; j < 8; ++j)
                xb[j] = src[row * 128 + c8 + (ii * 8 + j) * 8];
            #pragma unroll
            for (int j = 0; j < 8; ++j) {
                const float4 x = xb[j];
                if (j & 1) ss1 = fmaf(x.x, x.x, fmaf(x.y, x.y, fmaf(x.z, x.z, fmaf(x.w, x.w, ss1))));
                else       ss0 = fmaf(x.x, x.x, fmaf(x.y, x.y, fmaf(x.z, x.z, fmaf(x.w, x.w, ss0))));
                const int c4 = c8 + (ii * 8 + j) * 8;
                const int g = c4 >> 1, half = c4 & 1;
                ushort4 u;
                u.x = __builtin_bit_cast(unsigned short, (bf16)x.x);
                u.y = __builtin_bit_cast(unsigned short, (bf16)x.y);
                u.z = __builtin_bit_cast(unsigned short, (bf16)x.z);
                u.w = __builtin_bit_cast(unsigned short, (bf16)x.w);
                *(ushort4*)&tile[row * 512 + (((g ^ (row & 7)) << 3) + half * 4)] = u;
            }
        }
        {   // 8-lane reduce per row (rows are lane-aligned groups of 8)
            float ss = ss0 + ss1;
            ss += __shfl_xor(ss, 1);
            ss += __shfl_xor(ss, 2);
            ss += __shfl_xor(ss, 4);
            if (c8 == 0) pnorm[row] = ss;
        }
        __syncthreads();
        if (tid < 32)
            rs[v0 + tid] = 10.0f / fmaxf(sqrtf(pnorm[tid]), 1e-8f);   // folds 1/TEMP

        // 2: embS frag-major (uint4 LDS reads, coalesced global writes), 8 iters
        #pragma unroll
        for (int i = 0; i < 8; ++i) {
            const int F = i * 256 + tid;           // out granule 0..2047
            const int frag = F >> 6, l = F & 63;
            const int vt = frag >> 4, kf = frag & 15;   // vt 0..1
            const int lm = l & 15, lg = l >> 4;
            const int r = vt * 16 + lm, g = kf * 4 + lg;
            const uint4 d = *(const uint4*)&tile[r * 512 + ((g ^ (r & 7)) << 3)];
            *(uint4*)((unsigned short*)embS + ((size_t)(b * 2 + vt) * 16 + kf) * 512 + l * 8) = d;
        }
        // 3: embT frag-major (transpose gather from LDS, coalesced writes), 8 iters
        #pragma unroll
        for (int i = 0; i < 8; ++i) {
            const int F = i * 256 + tid;
            const int tt = F >> 6, l = F & 63;     // tt 0..31
            const int lm = l & 15, lg = l >> 4;
            const int t = tt * 16 + lm;
            unsigned short e[8];
            #pragma unroll
            for (int j = 0; j < 8; ++j) {
                const int r = lg * 8 + j;          // 0..31
                e[j] = tile[r * 512 + ((((t >> 3) ^ (r & 7)) << 3) + (t & 7))];
            }
            uint4 o;
            o.x = (unsigned)e[0] | ((unsigned)e[1] << 16);
            o.y = (unsigned)e[2] | ((unsigned)e[3] << 16);
            o.z = (unsigned)e[4] | ((unsigned)e[5] << 16);
            o.w = (unsigned)e[6] | ((unsigned)e[7] << 16);
            *(uint4*)((unsigned short*)embT + ((size_t)b * 32 + tt) * 512 + l * 8) = o;
        }
    } else {
        // ===================== proj branch (kw = audio@W + b, normalize) ====
        float* a_lds  = (float*)smem;                  // 4*768
        float* kw_lds = (float*)(smem + 12288);        // 4*512
        float* rn_lds = (float*)(smem + 20480);        // 4
        const int pb = blockIdx.x;
        const int q0 = pb * 4;

        // zero Oacc+Lsum slice (replaces hipMemsetAsync node): 513 float4/block
        for (int j = tid; j < 513; j += 256) zbase[pb * 513 + j] = float4{0.f, 0.f, 0.f, 0.f};

        const float4* asrc = (const float4*)(audio + q0 * 768);
        float4* adst = (float4*)a_lds;
        #pragma unroll
        for (int i = 0; i < 3; ++i) adst[i * 256 + tid] = asrc[i * 256 + tid];
        __syncthreads();

        // 16-deep register double-buffered W stream: 48 rounds, 32 loads in
        // flight while 128 FMAs execute -> latency covered, serial depth 48.
        float acc0[4] = {0.f, 0.f, 0.f, 0.f}, acc1[4] = {0.f, 0.f, 0.f, 0.f};
        float wa[16], wb[16];
        #pragma unroll
        for (int k = 0; k < 16; ++k) {
            wa[k] = W[k * 512 + tid];
            wb[k] = W[k * 512 + 256 + tid];
        }
        for (int dd = 0; dd < 48; ++dd) {
            float na[16], nb[16];
            if (dd < 47) {
                const int base = (dd + 1) * 16;
                #pragma unroll
                for (int k = 0; k < 16; ++k) {
                    na[k] = W[(base + k) * 512 + tid];
                    nb[k] = W[(base + k) * 512 + 256 + tid];
                }
            }
            #pragma unroll
            for (int k = 0; k < 16; ++k) {
                const int d = dd * 16 + k;
                #pragma unroll
                for (int q = 0; q < 4; ++q) {
                    const float a = a_lds[q * 768 + d];   // broadcast, conflict-free
                    acc0[q] = fmaf(a, wa[k], acc0[q]);
                    acc1[q] = fmaf(a, wb[k], acc1[q]);
                }
            }
            #pragma unroll
            for (int k = 0; k < 16; ++k) { wa[k] = na[k]; wb[k] = nb[k]; }
        }
        const float b0 = bias[tid], b1 = bias[256 + tid];
        #pragma unroll
        for (int q = 0; q < 4; ++q) {
            kw_lds[q * 512 + tid]       = acc0[q] + b0;
            kw_lds[q * 512 + 256 + tid] = acc1[q] + b1;
        }
        __syncthreads();

        const int w = tid >> 6;
        {   // wave w handles row w
            float ss = 0.f;
            #pragma unroll
            for (int i = 0; i < 8; ++i) { const float x = kw_lds[w * 512 + lane + i * 64]; ss = fmaf(x, x, ss); }
            #pragma unroll
            for (int o = 1; o < 64; o <<= 1) ss += __shfl_xor(ss, o);
            if (lane == 0) rn_lds[w] = 1.0f / fmaxf(sqrtf(ss), 1e-8f);
        }
        __syncthreads();
        #pragma unroll
        for (int i = 0; i < 8; ++i) {
            const int idx = i * 256 + tid;
            const int q = idx >> 9;
            kwn[(q0 + q) * 512 + (idx & 511)] = (bf16)(kw_lds[idx] * rn_lds[q]);
        }
    }
}

// ---------------- Kernel C: M64 producer/consumer fused attention ------------
// Base = round-10 (117us structure: dist-2 3-buffer E streams, rs hoist, coarse
// flags, no setprio, full-loop releases). Single change vs round-10: swapped-
// operand producer S^T = mfma(E,Q) so each lane holds 4 CONSECUTIVE v per reg
// group -> P scatter becomes 16 conflict-free packed ds_write_b64 instead of
// 64 8-way-conflicted ds_write_b16, and rs becomes 4 float4 loads. Store
// mapping HW-verified in round 1 (passed absmax with unchanged consumer).
__global__ __launch_bounds__(768, 3) void k_attn(const bf16* __restrict__ kwn,
        const bf16* __restrict__ embS, const bf16* __restrict__ embT,
        const float* __restrict__ rs, float* __restrict__ Oacc,
        float* __restrict__ Lsum) {
    __shared__ unsigned short Qlds[64 * 512];       // 64 KB, XOR-swizzled granules
    __shared__ unsigned short Plds[2 * 16384];      // 64 KB: 2 slots x (64q x 256v)
    __shared__ int prod_done[2], cons_done[2];
    const int tid = threadIdx.x;
    const int s = blockIdx.x & (NSPLIT - 1), qt = blockIdx.x >> 4;
    const int q0 = qt * 64;
    const int wg = tid >> 6, lane = tid & 63, lm = lane & 15, lg = lane >> 4;

    if (tid < 2) { prod_done[tid] = 0; cons_done[tid] = 0; }
    if (tid < 512) {   // stage Q tile (64x512 bf16), granule-swizzled g' = g^(q&7)
        const uint4* src = (const uint4*)(kwn + q0 * 512);
        #pragma unroll
        for (int i = 0; i < 8; ++i) {
            const int L = (i * 512 + tid) * 8;
            const int q = L >> 9, g = (L & 511) >> 3;
            *(uint4*)&Qlds[q * 512 + ((g ^ (q & 7)) << 3)] = src[i * 512 + tid];
        }
    }
    __syncthreads();   // covers Q staging + flag init

    const f32x4 zero4 = {0.f, 0.f, 0.f, 0.f};
    const int c0 = (s * NCH) / NSPLIT, c1 = ((s + 1) * NCH) / NSPLIT;
    const int n = c1 - c0;

    if (wg < 4) {
        // ================= producer: v-slice wg*64, all 64 q =================
        // swapped-operand S^T: lane holds S[q = mb*16+lm][v = wg*64+nb*16+lg*4+r]
        float lacc[4] = {0.f, 0.f, 0.f, 0.f};   // per-lane P row-sum partial, q = mb*16+lm
        for (int i = 0; i < n; ++i) {
            const int c = c0 + i;
            const int slot = i & 1, use = i >> 1;
            // rs preload: off the post-wait critical path (flag-independent)
            float4 rs4[4];
            #pragma unroll
            for (int nb = 0; nb < 4; ++nb)
                rs4[nb] = ((const float4*)(rs + c * 256 + wg * 64 + nb * 16))[lg];
            // ---- S^T compute (flag-independent), distance-2 3-buffer E stream ----
            f32x4 sacc[4][4];
            #pragma unroll
            for (int mb = 0; mb < 4; ++mb)
                #pragma unroll
                for (int nb = 0; nb < 4; ++nb) sacc[mb][nb] = zero4;
            const bf16* Eb = embS + ((size_t)(c * 16 + wg * 4) * 16) * 512 + lane * 8;
            bf16x8 eb[3][4];
            #pragma unroll
            for (int nb = 0; nb < 4; ++nb) {
                eb[0][nb] = *(const bf16x8*)(Eb + (nb * 16) * 512);
                eb[1][nb] = *(const bf16x8*)(Eb + (nb * 16 + 1) * 512);
            }
            #pragma unroll
            for (int kf = 0; kf < 16; ++kf) {
                if (kf < 14) {     // distance-2 prefetch, static %3 rotation
                    #pragma unroll
                    for (int nb = 0; nb < 4; ++nb)
                        eb[(kf + 2) % 3][nb] = *(const bf16x8*)(Eb + (nb * 16 + kf + 2) * 512);
                }
                const int goff = ((kf * 4 + lg) ^ (lm & 7)) << 3;
                bf16x8 aq[4];
                #pragma unroll
                for (int mb = 0; mb < 4; ++mb)
                    aq[mb] = *(const bf16x8*)&Qlds[(mb * 16 + lm) * 512 + goff];
                #pragma unroll
                for (int nb = 0; nb < 4; ++nb)
                    #pragma unroll
                    for (int mb = 0; mb < 4; ++mb)
                        sacc[mb][nb] = __builtin_amdgcn_mfma_f32_16x16x32_bf16(eb[kf % 3][nb], aq[mb], sacc[mb][nb], 0, 0, 0);
                __builtin_amdgcn_sched_barrier(0);
            }
            // ---- wait slot free (8 consumers), then exp + packed writes ----
            while (__hip_atomic_load(&cons_done[slot], __ATOMIC_ACQUIRE,
                                     __HIP_MEMORY_SCOPE_WORKGROUP) < 8 * use)
                __builtin_amdgcn_s_sleep(1);
            unsigned short* Pw = Plds + (slot << 14);
            #pragma unroll
            for (int nb = 0; nb < 4; ++nb) {
                const float4 rv = rs4[nb];
                const int kfc = wg * 2 + (nb >> 1);
                const int off = (lm + 16 * ((nb & 1) * 2 + (lg >> 1))) * 8 + (lg & 1) * 4;
                #pragma unroll
                for (int mb = 0; mb < 4; ++mb) {
                    const bf16 b0 = (bf16)__expf(sacc[mb][nb][0] * rv.x);
                    const bf16 b1 = (bf16)__expf(sacc[mb][nb][1] * rv.y);
                    const bf16 b2 = (bf16)__expf(sacc[mb][nb][2] * rv.z);
                    const bf16 b3 = (bf16)__expf(sacc[mb][nb][3] * rv.w);
                    lacc[mb] += ((float)b0 + (float)b1) + ((float)b2 + (float)b3);
                    ushort4 w4;
                    w4.x = __builtin_bit_cast(unsigned short, b0);
                    w4.y = __builtin_bit_cast(unsigned short, b1);
                    w4.z = __builtin_bit_cast(unsigned short, b2);
                    w4.w = __builtin_bit_cast(unsigned short, b3);
                    *(ushort4*)&Pw[(mb * 8 + kfc) * 512 + off] = w4;   // packed b64
                }
            }
            if (lane == 0)   // ONE increment per wave (release drains LDS writes)
                __hip_atomic_fetch_add(&prod_done[slot], 1, __ATOMIC_RELEASE,
                                       __HIP_MEMORY_SCOPE_WORKGROUP);
        }
        // Lsum: lanes sharing lm hold partials for q = mb*16+lm; reduce over lg
        #pragma unroll
        for (int mb = 0; mb < 4; ++mb) {
            float sum = lacc[mb];
            sum += __shfl_xor(sum, 16);
            sum += __shfl_xor(sum, 32);
            if (lane < 16) atomicAdd(&Lsum[q0 + mb * 16 + lm], sum);
        }
    } else {
        // ================= consumer: t-slice (wg-4)*64, all 64 q =============
        const int cw = wg - 4;
        f32x4 acc[4][4];                   // [mb 16q][nt 16t]
        #pragma unroll
        for (int mb = 0; mb < 4; ++mb)
            #pragma unroll
            for (int nt = 0; nt < 4; ++nt) acc[mb][nt] = zero4;
        for (int i = 0; i < n; ++i) {
            const int cc = c0 + i;
            const int slot = i & 1, use = i >> 1;
            const bf16* ETb = embT + ((size_t)cc * 256 + cw * 4) * 512 + lane * 8;
            // distance-2 3-buffer ET stream; kf=0,1 issued BEFORE the flag wait
            bf16x8 et[3][4];
            #pragma unroll
            for (int nt = 0; nt < 4; ++nt) {
                et[0][nt] = *(const bf16x8*)(ETb + nt * 512);
                et[1][nt] = *(const bf16x8*)(ETb + (32 + nt) * 512);
            }
            while (__hip_atomic_load(&prod_done[slot], __ATOMIC_ACQUIRE,
                                     __HIP_MEMORY_SCOPE_WORKGROUP) < 4 * (use + 1))
                __builtin_amdgcn_s_sleep(1);
            const unsigned short* Pb = Plds + (slot << 14);
            #pragma unroll
            for (int kf = 0; kf < 8; ++kf) {
                if (kf < 6) {      // distance-2 prefetch, static %3 rotation
                    #pragma unroll
                    for (int nt = 0; nt < 4; ++nt)
                        et[(kf + 2) % 3][nt] = *(const bf16x8*)(ETb + ((kf + 2) * 32 + nt) * 512);
                }
                bf16x8 pf[4];
                #pragma unroll
                for (int mb = 0; mb < 4; ++mb)
                    pf[mb] = *(const bf16x8*)&Pb[(mb * 8 + kf) * 512 + lane * 8];
                #pragma unroll
                for (int nt = 0; nt < 4; ++nt)
                    #pragma unroll
                    for (int mb = 0; mb < 4; ++mb)
                        acc[mb][nt] = __builtin_amdgcn_mfma_f32_16x16x32_bf16(pf[mb], et[kf % 3][nt], acc[mb][nt], 0, 0, 0);
                __builtin_amdgcn_sched_barrier(0);
            }
            if (lane == 0)   // ONE increment per wave (release drains LDS reads)
                __hip_atomic_fetch_add(&cons_done[slot], 1, __ATOMIC_RELEASE,
                                       __HIP_MEMORY_SCOPE_WORKGROUP);
        }
        // epilogue: combine partials across v-splits
        #pragma unroll
        for (int mb = 0; mb < 4; ++mb)
            #pragma unroll
            for (int nt = 0; nt < 4; ++nt)
                #pragma unroll
                for (int r = 0; r < 4; ++r) {
                    const int q = q0 + mb * 16 + lg * 4 + r;
                    const int t = cw * 64 + nt * 16 + lm;
                    atomicAdd(&Oacc[q * 512 + t], acc[mb][nt][r]);
                }
    }
}

// ---------------- Kernel D: out = Oacc / Lsum --------------------------------
__global__ __launch_bounds__(256) void k_final(const float* __restrict__ Oacc,
        const float* __restrict__ Lsum, float* __restrict__ out) {
    const int i = blockIdx.x * 256 + threadIdx.x;   // float4 index, 131072 total
    const float4 o = ((const float4*)Oacc)[i];
    const float inv = 1.0f / Lsum[i >> 7];          // 128 float4 per row
    float4 r;
    r.x = o.x * inv; r.y = o.y * inv; r.z = o.z * inv; r.w = o.w * inv;
    ((float4*)out)[i] = r;
}

// ---------------- launcher ---------------------------------------------------
// ws layout (bytes) — total 104,535,040 (proven to fit):
//   0        kwn   bf16 [1024*512]          1,048,576
//   1048576  rs    f32  [49408]               197,632
//   1246208  Oacc  f32  [1024*512]          2,097,152   (zeroed by k_pre proj blocks)
//   3343360  Lsum  f32  [1024]                   4,096   (zeroed by k_pre proj blocks)
//   3347456  embS  bf16 frag-major          50,593,792
//   53941248 embT  bf16 frag-major          50,593,792
extern "C" void kernel_launch(void* const* d_in, const int* in_sizes, int n_in,
                              void* d_out, int out_size, void* d_ws, size_t ws_size,
                              hipStream_t stream) {
    const float* audio = (const float*)d_in[0];
    const float* W     = (const float*)d_in[1];
    const float* bias  = (const float*)d_in[2];
    const float* emb   = (const float*)d_in[3];
    float* out = (float*)d_out;
    char* ws = (char*)d_ws;

    bf16*  kwn  = (bf16*)(ws);
    float* rs   = (float*)(ws + 1048576);
    float* Oacc = (float*)(ws + 1246208);
    float* Lsum = (float*)(ws + 3343360);
    bf16*  embS = (bf16*)(ws + 3347456);
    bf16*  embT = (bf16*)(ws + 53941248);
    float4* zbase = (float4*)(ws + 1246208);        // Oacc+Lsum contiguous, 131328 float4

    k_pre<<<NPROJ + NPREPB, 256, 0, stream>>>(emb, embS, embT, rs, audio, W, bias, kwn, zbase);
    k_attn<<<NQT * NSPLIT, 768, 0, stream>>>(kwn, embS, embT, rs, Oacc, Lsum);
    k_final<<<(out_size / 4) / 256, 256, 0, stream>>>(Oacc, Lsum, out);
}